// Round 17
// baseline (955.148 us; speedup 1.0000x reference)
//
#include <hip/hip_runtime.h>

// ---------------- problem constants ----------------
constexpr int Bc   = 2;
constexpr int Tc   = 4096;
constexpr int Dc   = 2048;
constexpr int Hc   = 16;
constexpr int Kc   = 128;
constexpr int Pc   = Hc * Kc;     // 2048
constexpr int Cc   = 64;          // chunk size
constexpr int NCc  = Tc / Cc;     // 64 chunks
constexpr int Mc   = Bc * Tc;     // 8192 rows
constexpr int LATc = 128;

// ---------------- helpers ----------------
__device__ __forceinline__ float bf2f(unsigned short u) {
  unsigned int x = ((unsigned int)u) << 16;
  return __builtin_bit_cast(float, x);
}
__device__ __forceinline__ unsigned short f2bf(float f) {
  unsigned int x = __builtin_bit_cast(unsigned int, f);
  x += 0x7fffu + ((x >> 16) & 1u);
  return (unsigned short)(x >> 16);
}
__device__ __forceinline__ float4 ld4(const float* p) {
  return *reinterpret_cast<const float4*>(p);
}
__device__ __forceinline__ float4 ld4(const unsigned short* p) {
  ushort4 u = *reinterpret_cast<const ushort4*>(p);
  return make_float4(bf2f(u.x), bf2f(u.y), bf2f(u.z), bf2f(u.w));
}
__device__ __forceinline__ void st1(float* p, float v) { *p = v; }
__device__ __forceinline__ void st1(unsigned short* p, float v) { *p = f2bf(v); }

// fast transcendentals (native v_exp_f32 / v_log_f32 / v_rcp_f32)
__device__ __forceinline__ float fsig(float x) {
  return __fdividef(1.f, 1.f + __expf(-x));
}
__device__ __forceinline__ float fsoftplus(float g) {
  return (g > 20.f) ? g : __logf(1.f + __expf(g));
}

typedef __attribute__((ext_vector_type(8))) short bf16x8;
typedef __attribute__((ext_vector_type(4))) float f32x4;

// LDS swizzles: rows of stride 256B (swzA), 128B (swzB), 64B (swzC)
__device__ __forceinline__ int swzA(int row, int kbyte) { return row * 256 + (kbyte ^ ((row & 7) << 4)); }
__device__ __forceinline__ int swzB(int row, int kbyte) { return row * 128 + (kbyte ^ ((row & 7) << 4)); }
__device__ __forceinline__ int swzC(int row, int kbyte) { return row * 64 + (kbyte ^ (((row >> 2) & 3) << 4)); }
__device__ __forceinline__ bf16x8 ldsv8(const unsigned short* base, int byteoff) {
  return *reinterpret_cast<const bf16x8*>(reinterpret_cast<const char*>(base) + byteoff);
}
__device__ __forceinline__ void stsv16B(unsigned short* base, int byteoff, int4 v) {
  *reinterpret_cast<int4*>(reinterpret_cast<char*>(base) + byteoff) = v;
}
__device__ __forceinline__ void stsv8B(unsigned short* base, int byteoff, uint2 v) {
  *reinterpret_cast<uint2*>(reinterpret_cast<char*>(base) + byteoff) = v;
}
__device__ __forceinline__ unsigned short lds16(const unsigned short* base, int byteoff) {
  return *reinterpret_cast<const unsigned short*>(reinterpret_cast<const char*>(base) + byteoff);
}

// bijective XCD-aware block swizzle (T1); identity unless nwg%8==0 && nwg>=16
__device__ __forceinline__ int xcd_swz(int id, int nwg) {
  if ((nwg & 7) != 0 || nwg < 16) return id;
  return (id & 7) * (nwg >> 3) + (id >> 3);
}

// ---------------- f32 -> bf16 cast ----------------
__global__ void cast_f32_bf16(const float* __restrict__ in, unsigned short* __restrict__ out,
                              int n) {
  int i = (blockIdx.x * 256 + threadIdx.x) * 4;
  if (i < n) {
    float4 v = ld4(in + i);
    ushort4 o;
    o.x = f2bf(v.x); o.y = f2bf(v.y); o.z = f2bf(v.z); o.w = f2bf(v.w);
    *reinterpret_cast<ushort4*>(out + i) = o;
  }
}

// ---------------- bf16 MFMA NT GEMMs ----------------
// k-group permutation (kg ^= (row>>1)&3) keeps ds_read_b128 fragment reads
// conflict-free (rule #21: linear gload dest + permuted SOURCE + permuted READ).
__device__ __forceinline__ void gload_lds16(const unsigned short* g, unsigned short* l) {
  __builtin_amdgcn_global_load_lds(
      (const __attribute__((address_space(1))) void*)g,
      (__attribute__((address_space(3))) void*)l, 16, 0, 0);
}

// GROUP_M=8 raster for 128-row tiles; per-XCD A-panel = 8x128 rows x 4KB = 4MB L2
__device__ __forceinline__ void tile_map(int& m0, int& n0) {
  int id = blockIdx.y * gridDim.x + blockIdx.x;
  id = xcd_swz(id, gridDim.x * gridDim.y);
  const int bpg = gridDim.y << 3;
  int grp = id / bpg, rem = id % bpg;
  m0 = ((grp << 3) + (rem & 7)) * 128;
  n0 = (rem >> 3) * 128;
}

// ---- 2-wave 128x128 tile: each wave owns 64x128 (4x8 frags); 12 ds_reads / 32 MFMA
// per K-step per wave (vs 8/16 in the 4-wave variant) -> -25% block LDS traffic,
// 128-thr blocks -> ~4 blocks/CU of independent 2-wave barrier groups.
template <typename OT>
__global__ __launch_bounds__(128) void gemm_nt_mfma2(const unsigned short* __restrict__ A,
                                                     const unsigned short* __restrict__ Bm,
                                                     OT* __restrict__ Out,
                                                     int Ndim, int Kd) {
  __shared__ __align__(16) unsigned short As[128 * 32];
  __shared__ __align__(16) unsigned short Bs[128 * 32];
  int m0, n0;
  tile_map(m0, n0);
  const int tid = threadIdx.x;       // 0..127
  const int wave = tid >> 6;         // 0..1
  const int lane = tid & 63;
  const int l15 = lane & 15, l4 = lane >> 4;
  const int kxor = (l4 ^ ((l15 >> 1) & 3)) << 3;
  f32x4 acc[4][8] = {};

  for (int k0 = 0; k0 < Kd; k0 += 32) {
#pragma unroll
    for (int i = 0; i < 4; ++i) {
      int slot = i * 128 + tid;       // 0..511 (16B slots of the 128x32 tile)
      int r = slot >> 2;
      int kg = (slot & 3) ^ ((r >> 1) & 3);
      gload_lds16(&A[(size_t)(m0 + r) * Kd + k0 + kg * 8], &As[i * 1024 + wave * 512]);
    }
#pragma unroll
    for (int i = 0; i < 4; ++i) {
      int slot = i * 128 + tid;
      int r = slot >> 2;
      int kg = (slot & 3) ^ ((r >> 1) & 3);
      gload_lds16(&Bm[(size_t)(n0 + r) * Kd + k0 + kg * 8], &Bs[i * 1024 + wave * 512]);
    }
    __syncthreads();
    bf16x8 af[4], bfr[8];
#pragma unroll
    for (int m = 0; m < 4; ++m)
      af[m] = *reinterpret_cast<const bf16x8*>(&As[(wave * 64 + m * 16 + l15) * 32 + kxor]);
#pragma unroll
    for (int n = 0; n < 8; ++n)
      bfr[n] = *reinterpret_cast<const bf16x8*>(&Bs[(n * 16 + l15) * 32 + kxor]);
#pragma unroll
    for (int m = 0; m < 4; ++m)
#pragma unroll
      for (int n = 0; n < 8; ++n)
        acc[m][n] = __builtin_amdgcn_mfma_f32_16x16x32_bf16(af[m], bfr[n], acc[m][n], 0, 0, 0);
    __syncthreads();
  }
#pragma unroll
  for (int m = 0; m < 4; ++m)
#pragma unroll
    for (int n = 0; n < 8; ++n)
#pragma unroll
      for (int r = 0; r < 4; ++r) {
        int row = m0 + wave * 64 + m * 16 + l4 * 4 + r;
        int col = n0 + n * 16 + l15;
        st1(&Out[(size_t)row * Ndim + col], acc[m][n][r]);
      }
}

// ---- 2-wave fused QKV variant: B = [Wq;Wk;Wv] (6144 rows); col>>11 picks buffer ----
__global__ __launch_bounds__(128) void gemm_nt_mfma_qkv2(const unsigned short* __restrict__ A,
                                                         const unsigned short* __restrict__ Bm,
                                                         unsigned short* __restrict__ Out,
                                                         int Kd) {
  __shared__ __align__(16) unsigned short As[128 * 32];
  __shared__ __align__(16) unsigned short Bs[128 * 32];
  int m0, n0;
  tile_map(m0, n0);
  const int tid = threadIdx.x;
  const int wave = tid >> 6;
  const int lane = tid & 63;
  const int l15 = lane & 15, l4 = lane >> 4;
  const int kxor = (l4 ^ ((l15 >> 1) & 3)) << 3;
  f32x4 acc[4][8] = {};

  for (int k0 = 0; k0 < Kd; k0 += 32) {
#pragma unroll
    for (int i = 0; i < 4; ++i) {
      int slot = i * 128 + tid;
      int r = slot >> 2;
      int kg = (slot & 3) ^ ((r >> 1) & 3);
      gload_lds16(&A[(size_t)(m0 + r) * Kd + k0 + kg * 8], &As[i * 1024 + wave * 512]);
    }
#pragma unroll
    for (int i = 0; i < 4; ++i) {
      int slot = i * 128 + tid;
      int r = slot >> 2;
      int kg = (slot & 3) ^ ((r >> 1) & 3);
      gload_lds16(&Bm[(size_t)(n0 + r) * Kd + k0 + kg * 8], &Bs[i * 1024 + wave * 512]);
    }
    __syncthreads();
    bf16x8 af[4], bfr[8];
#pragma unroll
    for (int m = 0; m < 4; ++m)
      af[m] = *reinterpret_cast<const bf16x8*>(&As[(wave * 64 + m * 16 + l15) * 32 + kxor]);
#pragma unroll
    for (int n = 0; n < 8; ++n)
      bfr[n] = *reinterpret_cast<const bf16x8*>(&Bs[(n * 16 + l15) * 32 + kxor]);
#pragma unroll
    for (int m = 0; m < 4; ++m)
#pragma unroll
      for (int n = 0; n < 8; ++n)
        acc[m][n] = __builtin_amdgcn_mfma_f32_16x16x32_bf16(af[m], bfr[n], acc[m][n], 0, 0, 0);
    __syncthreads();
  }
  unsigned short* dst = Out + (size_t)(n0 >> 11) * ((size_t)Mc * 2048);
  const int cbase = n0 & 2047;
#pragma unroll
  for (int m = 0; m < 4; ++m)
#pragma unroll
    for (int n = 0; n < 8; ++n)
#pragma unroll
      for (int r = 0; r < 4; ++r) {
        int row = m0 + wave * 64 + m * 16 + l4 * 4 + r;
        int col = cbase + n * 16 + l15;
        dst[(size_t)row * 2048 + col] = f2bf(acc[m][n][r]);
      }
}

// ---- fused fa/ga/beta variant (4-wave 128x128): B = [Wfa;Wga;Wb_pad]; grid (64,3) ----
__global__ __launch_bounds__(256) void gemm_nt_mfma_fgb(const unsigned short* __restrict__ A,
                                                        const unsigned short* __restrict__ Bm,
                                                        unsigned short* __restrict__ fab,
                                                        unsigned short* __restrict__ gab,
                                                        unsigned short* __restrict__ betabb,
                                                        int Kd) {
  __shared__ __align__(16) unsigned short As[128 * 32];
  __shared__ __align__(16) unsigned short Bs[128 * 32];
  int m0, n0;
  tile_map(m0, n0);
  const int tid = threadIdx.x;
  const int wave = tid >> 6;
  const int lane = tid & 63;
  const int wr = wave >> 1, wc = wave & 1;
  const int l15 = lane & 15, l4 = lane >> 4;
  const int kxor = (l4 ^ ((l15 >> 1) & 3)) << 3;
  f32x4 acc[4][4] = {};

  for (int k0 = 0; k0 < Kd; k0 += 32) {
#pragma unroll
    for (int i = 0; i < 2; ++i) {
      int slot = (wave * 2 + i) * 64 + lane;
      int r = slot >> 2;
      int kg = (slot & 3) ^ ((r >> 1) & 3);
      gload_lds16(&A[(size_t)(m0 + r) * Kd + k0 + kg * 8], &As[(wave * 2 + i) * 512]);
      gload_lds16(&Bm[(size_t)(n0 + r) * Kd + k0 + kg * 8], &Bs[(wave * 2 + i) * 512]);
    }
    __syncthreads();
    bf16x8 af[4], bfr[4];
#pragma unroll
    for (int m = 0; m < 4; ++m)
      af[m] = *reinterpret_cast<const bf16x8*>(&As[(wr * 64 + m * 16 + l15) * 32 + kxor]);
#pragma unroll
    for (int n = 0; n < 4; ++n)
      bfr[n] = *reinterpret_cast<const bf16x8*>(&Bs[(wc * 64 + n * 16 + l15) * 32 + kxor]);
#pragma unroll
    for (int m = 0; m < 4; ++m)
#pragma unroll
      for (int n = 0; n < 4; ++n)
        acc[m][n] = __builtin_amdgcn_mfma_f32_16x16x32_bf16(af[m], bfr[n], acc[m][n], 0, 0, 0);
    __syncthreads();
  }
  unsigned short* dst = (n0 == 0) ? fab : ((n0 == 128) ? gab : betabb);
#pragma unroll
  for (int m = 0; m < 4; ++m)
#pragma unroll
    for (int n = 0; n < 4; ++n)
#pragma unroll
      for (int r = 0; r < 4; ++r) {
        int row = m0 + wr * 64 + m * 16 + l4 * 4 + r;
        int lc = wc * 64 + n * 16 + l15;
        dst[(size_t)row * 128 + lc] = f2bf(acc[m][n][r]);
      }
}

// ---- splitK variant (4-wave 128x128) ----
__global__ __launch_bounds__(256) void gemm_nt_mfma_sk(const unsigned short* __restrict__ A,
                                                       const unsigned short* __restrict__ Bm,
                                                       float* __restrict__ Part,
                                                       int Ndim, int Kd, int kslice, int Mtot) {
  __shared__ __align__(16) unsigned short As[128 * 32];
  __shared__ __align__(16) unsigned short Bs[128 * 32];
  const int m0 = blockIdx.x * 128;
  const int n0 = blockIdx.y * 128;
  const int kz = blockIdx.z * kslice;
  const int tid = threadIdx.x;
  const int wave = tid >> 6;
  const int lane = tid & 63;
  const int wr = wave >> 1, wc = wave & 1;
  const int l15 = lane & 15, l4 = lane >> 4;
  const int kxor = (l4 ^ ((l15 >> 1) & 3)) << 3;
  f32x4 acc[4][4] = {};

  for (int k0 = kz; k0 < kz + kslice; k0 += 32) {
#pragma unroll
    for (int i = 0; i < 2; ++i) {
      int slot = (wave * 2 + i) * 64 + lane;
      int r = slot >> 2;
      int kg = (slot & 3) ^ ((r >> 1) & 3);
      gload_lds16(&A[(size_t)(m0 + r) * Kd + k0 + kg * 8], &As[(wave * 2 + i) * 512]);
      gload_lds16(&Bm[(size_t)(n0 + r) * Kd + k0 + kg * 8], &Bs[(wave * 2 + i) * 512]);
    }
    __syncthreads();
    bf16x8 af[4], bfr[4];
#pragma unroll
    for (int m = 0; m < 4; ++m)
      af[m] = *reinterpret_cast<const bf16x8*>(&As[(wr * 64 + m * 16 + l15) * 32 + kxor]);
#pragma unroll
    for (int n = 0; n < 4; ++n)
      bfr[n] = *reinterpret_cast<const bf16x8*>(&Bs[(wc * 64 + n * 16 + l15) * 32 + kxor]);
#pragma unroll
    for (int m = 0; m < 4; ++m)
#pragma unroll
      for (int n = 0; n < 4; ++n)
        acc[m][n] = __builtin_amdgcn_mfma_f32_16x16x32_bf16(af[m], bfr[n], acc[m][n], 0, 0, 0);
    __syncthreads();
  }
  float* out = Part + (size_t)blockIdx.z * Mtot * Ndim;
#pragma unroll
  for (int m = 0; m < 4; ++m)
#pragma unroll
    for (int n = 0; n < 4; ++n)
#pragma unroll
      for (int r = 0; r < 4; ++r) {
        int row = m0 + wr * 64 + m * 16 + l4 * 4 + r;
        int col = n0 + wc * 64 + n * 16 + l15;
        out[(size_t)row * Ndim + col] = acc[m][n][r];
      }
}

// ---------------- chunk prep: one WAVE per chunk ----------------
// grid: Bc*Hc*NCc/4 = 512 blocks x 256 threads (4 waves = 4 chunks)
__global__ __launch_bounds__(256) void chunk_prep(
    const unsigned short* __restrict__ q_lin, const unsigned short* __restrict__ k_lin,
    const unsigned short* __restrict__ v_lin, const unsigned short* __restrict__ g_raw,
    const unsigned short* __restrict__ beta16, const float* __restrict__ conv_q,
    const float* __restrict__ conv_k, const float* __restrict__ conv_v,
    const float* __restrict__ A_log, const float* __restrict__ dt_bias,
    unsigned short* __restrict__ qt, unsigned short* __restrict__ u_,
    unsigned short* __restrict__ bv, unsigned short* __restrict__ bw,
    float* __restrict__ wlast) {
  const int wave = threadIdx.x >> 6, lane = threadIdx.x & 63;
  const int cid = blockIdx.x * 4 + wave;  // (b*H+h)*NC + n
  const int n = cid & 63;
  const int h = (cid >> 6) & 15;
  const int b = cid >> 10;
  const int k0 = 2 * lane;
  const int p = h * Kc + k0;
  float cq[2][4], ck[2][4], cv[2][4];
#pragma unroll
  for (int s = 0; s < 2; ++s)
#pragma unroll
    for (int j = 0; j < 4; ++j) {
      cq[s][j] = conv_q[(p + s) * 4 + j];
      ck[s][j] = conv_k[(p + s) * 4 + j];
      cv[s][j] = conv_v[(p + s) * 4 + j];
    }
  const float aneg = -__expf(A_log[h]);
  const float db0 = dt_bias[p], db1 = dt_bias[p + 1];
  float cum0 = 0.f, cum1 = 0.f;
  const int t0 = n * Cc;
  float wq[2][3] = {}, wk[2][3] = {}, wv[2][3] = {};
#pragma unroll
  for (int d = 0; d < 3; ++d) {
    int ts = t0 - 3 + d;
    if (ts >= 0) {
      size_t o = ((size_t)(b * Tc + ts)) * Pc + p;
      ushort2 q2 = *(const ushort2*)(q_lin + o);
      ushort2 k2 = *(const ushort2*)(k_lin + o);
      ushort2 v2 = *(const ushort2*)(v_lin + o);
      wq[0][d] = bf2f(q2.x); wq[1][d] = bf2f(q2.y);
      wk[0][d] = bf2f(k2.x); wk[1][d] = bf2f(k2.y);
      wv[0][d] = bf2f(v2.x); wv[1][d] = bf2f(v2.y);
    }
  }
  for (int c = 0; c < Cc; ++c) {
    const int t = t0 + c;
    size_t off = ((size_t)(b * Tc + t)) * Pc + p;
    ushort2 q2 = *(const ushort2*)(q_lin + off);
    ushort2 k2 = *(const ushort2*)(k_lin + off);
    ushort2 v2 = *(const ushort2*)(v_lin + off);
    ushort2 g2 = *(const ushort2*)(g_raw + off);
    float nq[2] = {bf2f(q2.x), bf2f(q2.y)};
    float nk[2] = {bf2f(k2.x), bf2f(k2.y)};
    float nv[2] = {bf2f(v2.x), bf2f(v2.y)};
    float qv[2], kv[2], vv[2];
#pragma unroll
    for (int s = 0; s < 2; ++s) {
      qv[s] = cq[s][0] * wq[s][0] + cq[s][1] * wq[s][1] + cq[s][2] * wq[s][2] + cq[s][3] * nq[s];
      kv[s] = ck[s][0] * wk[s][0] + ck[s][1] * wk[s][1] + ck[s][2] * wk[s][2] + ck[s][3] * nk[s];
      vv[s] = cv[s][0] * wv[s][0] + cv[s][1] * wv[s][1] + cv[s][2] * wv[s][2] + cv[s][3] * nv[s];
      wq[s][0] = wq[s][1]; wq[s][1] = wq[s][2]; wq[s][2] = nq[s];
      wk[s][0] = wk[s][1]; wk[s][1] = wk[s][2]; wk[s][2] = nk[s];
      wv[s][0] = wv[s][1]; wv[s][1] = wv[s][2]; wv[s][2] = nv[s];
      qv[s] = qv[s] * fsig(qv[s]);  // silu
      kv[s] = kv[s] * fsig(kv[s]);
      vv[s] = vv[s] * fsig(vv[s]);
    }
    float a = qv[0] * qv[0] + qv[1] * qv[1];
    float bb = kv[0] * kv[0] + kv[1] * kv[1];
#pragma unroll
    for (int off2 = 32; off2 > 0; off2 >>= 1) {
      a += __shfl_xor(a, off2, 64);
      bb += __shfl_xor(bb, off2, 64);
    }
    float rq = rsqrtf(a + 1e-12f) * 0.08838834764831845f;  // * K^-0.5
    float rk = rsqrtf(bb + 1e-12f);
    float g0 = bf2f(g2.x) + db0, g1 = bf2f(g2.y) + db1;
    cum0 += aneg * fsoftplus(g0);
    cum1 += aneg * fsoftplus(g1);
    float cc0 = fmaxf(cum0, -15.f), cc1 = fmaxf(cum1, -15.f);
    float Wg0 = __expf(cc0), Wg1 = __expf(cc1);
    float Wi0 = __fdividef(1.f, Wg0), Wi1 = __fdividef(1.f, Wg1);
    float beta = fsig(bf2f(beta16[((size_t)(b * Tc + t)) * 128 + h]));
    size_t idx = ((size_t)cid * Cc + c) * Kc + k0;
    ushort2 o1, o2, o3, o4;
    o1.x = f2bf(qv[0] * rq * Wg0); o1.y = f2bf(qv[1] * rq * Wg1);
    o2.x = f2bf(kv[0] * rk * Wi0); o2.y = f2bf(kv[1] * rk * Wi1);
    o3.x = f2bf(beta * kv[0] * rk * Wg0); o3.y = f2bf(beta * kv[1] * rk * Wg1);
    o4.x = f2bf(beta * vv[0]); o4.y = f2bf(beta * vv[1]);
    *(ushort2*)(qt + idx) = o1;
    *(ushort2*)(u_ + idx) = o2;
    *(ushort2*)(bw + idx) = o3;
    *(ushort2*)(bv + idx) = o4;
    if (c == Cc - 1) {
      wlast[(size_t)cid * Kc + k0] = Wg0;
      wlast[(size_t)cid * Kc + k0 + 1] = Wg1;
    }
  }
}

// ---------------- MFMA chunk solve + in-place u -> u^T transpose ----------------
__global__ __launch_bounds__(256) void chunk_solve_mfma(
    const unsigned short* __restrict__ qt, unsigned short* __restrict__ u_,
    unsigned short* __restrict__ evb,  // in: bv, out: ev
    unsigned short* __restrict__ ewb,  // in: bw, out: ew
    unsigned short* __restrict__ intra_out) {
  const int blk = blockIdx.x;
  const size_t base = (size_t)blk * (Cc * Kc);
  const size_t ibase = (size_t)blk * (Cc * Cc);
  const int tid = threadIdx.x, wave = tid >> 6, lane = tid & 63;
  const int l15 = lane & 15, l4 = lane >> 4;

  __shared__ __align__(16) char lds[65536];
  unsigned short* uS   = (unsigned short*)(lds);            // [64][128] swzA
  unsigned short* qtS  = (unsigned short*)(lds + 16384);    // [64][128] swzA
  unsigned short* bwS  = (unsigned short*)(lds + 32768);    // [64][128] swzA
  unsigned short* NLrm = (unsigned short*)(lds + 49152);    // [64][64] swzB
  unsigned short* NLT  = (unsigned short*)(lds + 57344);    // [64][64] swzB
  unsigned short* Trm  = (unsigned short*)(lds);            // over uS
  unsigned short* TT   = (unsigned short*)(lds + 8192);
  unsigned short* Prm  = (unsigned short*)(lds + 16384);    // over qtS
  unsigned short* PT   = (unsigned short*)(lds + 24576);
  unsigned short* bvT  = (unsigned short*)(lds + 32768);    // [128][64] swzB, over bwS
  unsigned short* bwT  = (unsigned short*)(lds + 49152);    // [128][64] swzB, over NL

#pragma unroll
  for (int i = 0; i < 4; ++i) {
    int cid = tid + i * 256;
    int r = cid >> 4, c8 = (cid & 15) * 8, cb2 = (cid & 15) * 16;
    int4 vu = *(const int4*)(u_ + base + (size_t)r * 128 + c8);
    int4 vb = *(const int4*)(ewb + base + (size_t)r * 128 + c8);
    int4 vq = *(const int4*)(qt + base + (size_t)r * 128 + c8);
    stsv16B(uS, swzA(r, cb2), vu);
    stsv16B(bwS, swzA(r, cb2), vb);
    stsv16B(qtS, swzA(r, cb2), vq);
  }
  __syncthreads();

  const int arow = 16 * wave + l15;
  bf16x8 aBw[4], aQt[4];
#pragma unroll
  for (int ks = 0; ks < 4; ++ks) {
    aBw[ks] = ldsv8(bwS, swzA(arow, 16 * l4 + 64 * ks));
    aQt[ks] = ldsv8(qtS, swzA(arow, 16 * l4 + 64 * ks));
  }
  f32x4 Lc[4], Ic[4];
#pragma unroll
  for (int nt = 0; nt < 4; ++nt) {
    f32x4 a = {}, bq = {};
#pragma unroll
    for (int ks = 0; ks < 4; ++ks) {
      bf16x8 bu = ldsv8(uS, swzA(16 * nt + l15, 16 * l4 + 64 * ks));
      a = __builtin_amdgcn_mfma_f32_16x16x32_bf16(aBw[ks], bu, a, 0, 0, 0);
      bq = __builtin_amdgcn_mfma_f32_16x16x32_bf16(aQt[ks], bu, bq, 0, 0, 0);
    }
    Lc[nt] = a; Ic[nt] = bq;
  }
#pragma unroll
  for (int nt = 0; nt < 4; ++nt)
#pragma unroll
    for (int r = 0; r < 4; ++r) {
      int row = 16 * wave + 4 * l4 + r, col = 16 * nt + l15;
      intra_out[ibase + (size_t)row * 64 + col] = f2bf((col <= row) ? Ic[nt][r] : 0.f);
    }

  // in-place u^T write-back
#pragma unroll
  for (int i = 0; i < 4; ++i) {
    int w2 = tid + i * 256;
    int k = w2 >> 3, cg = w2 & 7;
    unsigned short tmp[8];
#pragma unroll
    for (int j = 0; j < 8; ++j) {
      int c = cg + 8 * j;
      tmp[j] = lds16(uS, swzA(c, 2 * k));
    }
#pragma unroll
    for (int j = 0; j < 8; ++j)
      u_[base + (size_t)k * 64 + cg + 8 * j] = tmp[j];
  }
  __syncthreads();

  f32x4 Tf[4];
#pragma unroll
  for (int nt = 0; nt < 4; ++nt)
#pragma unroll
    for (int r = 0; r < 4; ++r) {
      int row = 16 * wave + 4 * l4 + r, col = 16 * nt + l15;
      float nl = (col < row) ? -Lc[nt][r] : 0.f;
      unsigned short nb = f2bf(nl);
      *reinterpret_cast<unsigned short*>((char*)NLrm + swzB(row, col * 2)) = nb;
      *reinterpret_cast<unsigned short*>((char*)NLT + swzB(col, row * 2)) = nb;
      float t0 = nl + ((row == col) ? 1.f : 0.f);
      Tf[nt][r] = t0;
      unsigned short tb = f2bf(t0);
      *reinterpret_cast<unsigned short*>((char*)Trm + swzB(row, col * 2)) = tb;
      *reinterpret_cast<unsigned short*>((char*)TT + swzB(col, row * 2)) = tb;
    }
  __syncthreads();

  bf16x8 aN[2];
#pragma unroll
  for (int ks = 0; ks < 2; ++ks) aN[ks] = ldsv8(NLrm, swzB(arow, 16 * l4 + 64 * ks));
  f32x4 Pf[4];
#pragma unroll
  for (int nt = 0; nt < 4; ++nt) {
    f32x4 acc = {};
#pragma unroll
    for (int ks = 0; ks < 2; ++ks)
      acc = __builtin_amdgcn_mfma_f32_16x16x32_bf16(aN[ks], ldsv8(NLT, swzB(16 * nt + l15, 16 * l4 + 64 * ks)), acc, 0, 0, 0);
    Pf[nt] = acc;
  }
  int4 rv[4], rw[4];
#pragma unroll
  for (int i = 0; i < 4; ++i) {
    int cid = tid + i * 256;
    int r = cid >> 4, c8 = (cid & 15) * 8;
    rv[i] = *(const int4*)(evb + base + (size_t)r * 128 + c8);
    rw[i] = *(const int4*)(ewb + base + (size_t)r * 128 + c8);
  }
#pragma unroll
  for (int nt = 0; nt < 4; ++nt)
#pragma unroll
    for (int r = 0; r < 4; ++r) {
      int row = 16 * wave + 4 * l4 + r, col = 16 * nt + l15;
      unsigned short pb = f2bf(Pf[nt][r]);
      *reinterpret_cast<unsigned short*>((char*)Prm + swzB(row, col * 2)) = pb;
      *reinterpret_cast<unsigned short*>((char*)PT + swzB(col, row * 2)) = pb;
    }
  __syncthreads();

  for (int it = 0; it < 5; ++it) {
    bf16x8 aP[2];
#pragma unroll
    for (int ks = 0; ks < 2; ++ks) aP[ks] = ldsv8(Prm, swzB(arow, 16 * l4 + 64 * ks));
    f32x4 Tn[4], Pn[4];
#pragma unroll
    for (int nt = 0; nt < 4; ++nt) {
      f32x4 acc = Tf[nt];
#pragma unroll
      for (int ks = 0; ks < 2; ++ks)
        acc = __builtin_amdgcn_mfma_f32_16x16x32_bf16(aP[ks], ldsv8(TT, swzB(16 * nt + l15, 16 * l4 + 64 * ks)), acc, 0, 0, 0);
      Tn[nt] = acc;
    }
    if (it < 4) {
#pragma unroll
      for (int nt = 0; nt < 4; ++nt) {
        f32x4 acc = {};
#pragma unroll
        for (int ks = 0; ks < 2; ++ks)
          acc = __builtin_amdgcn_mfma_f32_16x16x32_bf16(aP[ks], ldsv8(PT, swzB(16 * nt + l15, 16 * l4 + 64 * ks)), acc, 0, 0, 0);
        Pn[nt] = acc;
      }
    }
    __syncthreads();
#pragma unroll
    for (int nt = 0; nt < 4; ++nt)
#pragma unroll
      for (int r = 0; r < 4; ++r) {
        int row = 16 * wave + 4 * l4 + r, col = 16 * nt + l15;
        unsigned short tb = f2bf(Tn[nt][r]);
        *reinterpret_cast<unsigned short*>((char*)Trm + swzB(row, col * 2)) = tb;
        *reinterpret_cast<unsigned short*>((char*)TT + swzB(col, row * 2)) = tb;
        if (it < 4) {
          unsigned short pb = f2bf(Pn[nt][r]);
          *reinterpret_cast<unsigned short*>((char*)Prm + swzB(row, col * 2)) = pb;
          *reinterpret_cast<unsigned short*>((char*)PT + swzB(col, row * 2)) = pb;
        }
      }
#pragma unroll
    for (int nt = 0; nt < 4; ++nt) Tf[nt] = Tn[nt];
    __syncthreads();
  }

#pragma unroll
  for (int i = 0; i < 4; ++i) {
    int cid = tid + i * 256;
    int r = cid >> 4;
    const unsigned short* pv = reinterpret_cast<const unsigned short*>(&rv[i]);
    const unsigned short* pw = reinterpret_cast<const unsigned short*>(&rw[i]);
#pragma unroll
    for (int j = 0; j < 8; ++j) {
      int v = (cid & 15) * 8 + j;
      *reinterpret_cast<unsigned short*>((char*)bvT + swzB(v, r * 2)) = pv[j];
      *reinterpret_cast<unsigned short*>((char*)bwT + swzB(v, r * 2)) = pw[j];
    }
  }
  __syncthreads();

  bf16x8 aT[2];
#pragma unroll
  for (int ks = 0; ks < 2; ++ks) aT[ks] = ldsv8(Trm, swzB(arow, 16 * l4 + 64 * ks));
#pragma unroll
  for (int nt = 0; nt < 8; ++nt) {
    f32x4 e = {}, w2 = {};
#pragma unroll
    for (int ks = 0; ks < 2; ++ks) {
      e = __builtin_amdgcn_mfma_f32_16x16x32_bf16(aT[ks], ldsv8(bvT, swzB(16 * nt + l15, 16 * l4 + 64 * ks)), e, 0, 0, 0);
      w2 = __builtin_amdgcn_mfma_f32_16x16x32_bf16(aT[ks], ldsv8(bwT, swzB(16 * nt + l15, 16 * l4 + 64 * ks)), w2, 0, 0, 0);
    }
#pragma unroll
    for (int r = 0; r < 4; ++r) {
      int row = 16 * wave + 4 * l4 + r, col = 16 * nt + l15;
      evb[base + (size_t)row * 128 + col] = f2bf(e[r]);
      ewb[base + (size_t)row * 128 + col] = f2bf(w2[r]);
    }
  }
}

// ---------------- MFMA scan, v-split x4: grid = B*H*4, 8 waves --------------------
__global__ __launch_bounds__(512) void scan_mfma(
    const unsigned short* __restrict__ qt, const unsigned short* __restrict__ uT,
    const unsigned short* __restrict__ evb, const unsigned short* __restrict__ ewb,
    const unsigned short* __restrict__ intra, const float* __restrict__ wlast,
    unsigned short* __restrict__ attn_o, unsigned short* __restrict__ snapb) {
  const int id = xcd_swz(blockIdx.x, 128);
  const int bh = id >> 2, vs = id & 3;
  const int b = bh >> 4, h = bh & 15;
  const int v0 = vs * 32;
  const int tid = threadIdx.x, wave = tid >> 6, lane = tid & 63;
  const int l15 = lane & 15, l4 = lane >> 4;
  __shared__ __align__(16) unsigned short ewS[8192];  // [64 c][128 k] swzA
  __shared__ __align__(16) unsigned short qtS[8192];  // [64 c][128 k] swzA
  __shared__ __align__(16) unsigned short uTS[8192];  // [128 k][64 c] swzB
  __shared__ __align__(16) unsigned short iaS[4096];  // [64 c][64 j]  swzB
  __shared__ __align__(16) unsigned short evS[2048];  // [64 c][32 v]  swzC (slice)
  __shared__ __align__(16) unsigned short sBT[4096];  // [32 v][128 k] swzA (S^T slice)
  __shared__ __align__(16) unsigned short dBT[2048];  // [32 v][64 c]  swzB (delta^T)

  f32x4 S[2] = {};
  {
    int4 z = {0, 0, 0, 0};
    stsv16B(sBT, tid * 16, z);  // 512 thr x 16B = 8KB
  }

  const int sr = tid >> 3;           // 0..63
  const int sk0 = (tid & 7) * 16;    // 128-wide col base
  const int sc0 = (tid & 7) * 8;     // 64-wide col base
  const int evc = (tid & 7) * 4;     // 32-wide col base (4 els)
  const int tk = tid >> 3;           // uT rows tk, tk+64
  const int wloff = 16 * wave + 4 * l4;
  int4 rEw0, rEw1, rQt0, rQt1, rUT0, rUT1, rIa;
  uint2 rEv;
  float4 rWlN, rWlC;

#define STAGE_LOAD(CB, IB, NN)                                                    \
  rEw0 = *(const int4*)(ewb + (CB) + sr * 128 + sk0);                             \
  rEw1 = *(const int4*)(ewb + (CB) + sr * 128 + sk0 + 8);                         \
  rQt0 = *(const int4*)(qt + (CB) + sr * 128 + sk0);                              \
  rQt1 = *(const int4*)(qt + (CB) + sr * 128 + sk0 + 8);                          \
  rEv = *(const uint2*)(evb + (CB) + sr * 128 + v0 + evc);                        \
  rUT0 = *(const int4*)(uT + (CB) + (size_t)tk * 64 + sc0);                       \
  rUT1 = *(const int4*)(uT + (CB) + (size_t)(tk + 64) * 64 + sc0);                \
  rIa = *(const int4*)(intra + (IB) + sr * 64 + sc0);                             \
  rWlN = ld4(wlast + ((size_t)bh * 64 + (NN)) * 128 + wloff);

#define STAGE_WRITE()                                                             \
  stsv16B(ewS, swzA(sr, sk0 * 2), rEw0);                                          \
  stsv16B(ewS, swzA(sr, sk0 * 2 + 16), rEw1);                                     \
  stsv16B(qtS, swzA(sr, sk0 * 2), rQt0);                                          \
  stsv16B(qtS, swzA(sr, sk0 * 2 + 16), rQt1);                                     \
  stsv8B(evS, swzC(sr, evc * 2), rEv);                                            \
  stsv16B(iaS, swzB(sr, sc0 * 2), rIa);                                           \
  stsv16B(uTS, swzB(tk, sc0 * 2), rUT0);                                          \
  stsv16B(uTS, swzB(tk + 64, sc0 * 2), rUT1);

  {
    const size_t cb0 = (size_t)bh * 64 * 8192;
    const size_t ib0 = (size_t)bh * 64 * 4096;
    STAGE_LOAD(cb0, ib0, 0);
    STAGE_WRITE();
    rWlC = rWlN;
  }
  __syncthreads();

  const int m = wave & 3, vg = wave >> 2;    // wave's o-tile = (m, vg)
  const int arow = 16 * m + l15;
  const int krow = 16 * wave + l15;
  const int vl = 16 * vg + l15;              // wave's v column (local)

  for (int n = 0; n < NCc; ++n) {
    const size_t cb = ((size_t)bh * 64 + n) * 8192;
    const size_t ib = ((size_t)bh * 64 + n) * 4096;
    // ---- Phase A: prefetch n+1; delta = ev - ew@S -> dBT ----
    if (n < 63) { STAGE_LOAD(cb + 8192, ib + 4096, n + 1); }
    bf16x8 aEw[4];
#pragma unroll
    for (int ks = 0; ks < 4; ++ks) aEw[ks] = ldsv8(ewS, swzA(arow, 16 * l4 + 64 * ks));
    {
      f32x4 p = {};
#pragma unroll
      for (int ks = 0; ks < 4; ++ks)
        p = __builtin_amdgcn_mfma_f32_16x16x32_bf16(aEw[ks], ldsv8(sBT, swzA(vl, 16 * l4 + 64 * ks)), p, 0, 0, 0);
      float d[4];
#pragma unroll
      for (int r = 0; r < 4; ++r) {
        int c = 16 * m + 4 * l4 + r;
        d[r] = bf2f(lds16(evS, swzC(c, 2 * vl))) - p[r];
      }
      uint2 pk;
      pk.x = (unsigned)f2bf(d[0]) | ((unsigned)f2bf(d[1]) << 16);
      pk.y = (unsigned)f2bf(d[2]) | ((unsigned)f2bf(d[3]) << 16);
      stsv8B(dBT, swzB(vl, (16 * m + 4 * l4) * 2), pk);
    }
    __syncthreads();
    // ---- Phase B1: o = qt@S + ia@delta; S = wl*(S + uT@delta) ----
    bf16x8 aQt[4], aIa[2], aU[2];
#pragma unroll
    for (int ks = 0; ks < 4; ++ks) aQt[ks] = ldsv8(qtS, swzA(arow, 16 * l4 + 64 * ks));
#pragma unroll
    for (int ks = 0; ks < 2; ++ks) aIa[ks] = ldsv8(iaS, swzB(arow, 16 * l4 + 64 * ks));
#pragma unroll
    for (int ks = 0; ks < 2; ++ks) aU[ks] = ldsv8(uTS, swzB(krow, 16 * l4 + 64 * ks));
    {
      f32x4 o = {};
#pragma unroll
      for (int ks = 0; ks < 4; ++ks)
        o = __builtin_amdgcn_mfma_f32_16x16x32_bf16(aQt[ks], ldsv8(sBT, swzA(vl, 16 * l4 + 64 * ks)), o, 0, 0, 0);
#pragma unroll
      for (int ks = 0; ks < 2; ++ks)
        o = __builtin_amdgcn_mfma_f32_16x16x32_bf16(aIa[ks], ldsv8(dBT, swzB(vl, 16 * l4 + 64 * ks)), o, 0, 0, 0);
#pragma unroll
      for (int r = 0; r < 4; ++r) {
        int c = 16 * m + 4 * l4 + r;
        int t = n * 64 + c;
        attn_o[((size_t)(b * Tc + t) * Hc + h) * Kc + v0 + vl] = f2bf(o[r]);
      }
    }
    float wlv[4] = {rWlC.x, rWlC.y, rWlC.z, rWlC.w};
#pragma unroll
    for (int vt2 = 0; vt2 < 2; ++vt2) {
      int vl2 = 16 * vt2 + l15;
      f32x4 U = {};
#pragma unroll
      for (int ks = 0; ks < 2; ++ks)
        U = __builtin_amdgcn_mfma_f32_16x16x32_bf16(aU[ks], ldsv8(dBT, swzB(vl2, 16 * l4 + 64 * ks)), U, 0, 0, 0);
#pragma unroll
      for (int r = 0; r < 4; ++r) S[vt2][r] = wlv[r] * (S[vt2][r] + U[r]);
    }
    __syncthreads();
    // ---- Phase B2: S -> sBT, staging writes, snapshot ----
#pragma unroll
    for (int vt2 = 0; vt2 < 2; ++vt2) {
      int vl2 = 16 * vt2 + l15;
      uint2 pk;
      pk.x = (unsigned)f2bf(S[vt2][0]) | ((unsigned)f2bf(S[vt2][1]) << 16);
      pk.y = (unsigned)f2bf(S[vt2][2]) | ((unsigned)f2bf(S[vt2][3]) << 16);
      stsv8B(sBT, swzA(vl2, (16 * wave + 4 * l4) * 2), pk);
    }
    if (n < 63) { STAGE_WRITE(); rWlC = rWlN; }
    if ((n & 3) == 3) {
      int ns = n >> 2;
      size_t sb = (size_t)((ns * Bc + b) * Hc + h) * 16384;
#pragma unroll
      for (int vt2 = 0; vt2 < 2; ++vt2)
#pragma unroll
        for (int r = 0; r < 4; ++r) {
          int k = 16 * wave + 4 * l4 + r;
          snapb[sb + (size_t)k * 128 + v0 + 16 * vt2 + l15] = f2bf(S[vt2][r]);
        }
    }
    __syncthreads();
  }
#undef STAGE_LOAD
#undef STAGE_WRITE
}

// ---------------- snapshot helpers ----------------
__global__ void sdw_mul_bf16(const float* __restrict__ snap_down, const float* __restrict__ w,
                             unsigned short* __restrict__ sdwb) {
  int i = (blockIdx.x * 256 + threadIdx.x) * 4;
  float4 v = ld4(snap_down + i);
  int k = i & 16383;
  float4 ww = ld4(w + k);
  ushort4 o;
  o.x = f2bf(v.x * ww.x); o.y = f2bf(v.y * ww.y); o.z = f2bf(v.z * ww.z); o.w = f2bf(v.w * ww.w);
  *reinterpret_cast<ushort4*>(sdwb + i) = o;
}

__global__ __launch_bounds__(256) void snap_scale_kernel(const unsigned short* __restrict__ snapb,
                                                         float* __restrict__ scale) {
  int r = blockIdx.x;
  const unsigned short* row = snapb + (size_t)r * 16384;
  float s = 0.f;
  for (int ii = threadIdx.x * 4; ii < 16384; ii += 1024) {
    float4 x = ld4(row + ii);
    s += x.x * x.x + x.y * x.y + x.z * x.z + x.w * x.w;
  }
#pragma unroll
  for (int off = 32; off > 0; off >>= 1) s += __shfl_down(s, off, 64);
  __shared__ float red[4];
  if ((threadIdx.x & 63) == 0) red[threadIdx.x >> 6] = s;
  __syncthreads();
  if (threadIdx.x == 0) {
    float tot = red[0] + red[1] + red[2] + red[3];
    scale[r] = rsqrtf(tot * (1.f / 16384.f) + 1e-6f);
  }
}

__global__ void snap_reduce_scatter(const float* __restrict__ part,
                                    const float* __restrict__ scale,
                                    float* __restrict__ outp) {
  int idx = blockIdx.x * 256 + threadIdx.x;
  int l = idx & 127;
  int hh = (idx >> 7) & 15;
  int ns = (idx >> 11) & 15;
  int bb = idx >> 15;
  int r = (ns * Bc + bb) * Hc + hh;
  float s = 0.f;
#pragma unroll
  for (int z = 0; z < 16; ++z) s += part[(size_t)z * 65536 + r * 128 + l];
  outp[idx] = s * scale[r];
}

// ---------------- final rmsnorm * sigmoid(gate): wave-per-row ----------
__global__ __launch_bounds__(256) void out_norm_gate(unsigned short* __restrict__ attn_io,
                                                     const unsigned short* __restrict__ gate_raw,
                                                     const float* __restrict__ bgb,
                                                     const float* __restrict__ o_norm_w) {
  const int wave = threadIdx.x >> 6, lane = threadIdx.x & 63;
  const int blk = blockIdx.x * 4 + wave;  // (b*T + t)*H + h
  const int h = blk & 15;
  const size_t row = (size_t)(blk >> 4);
  const size_t base = (size_t)blk * Kc;
  ushort2 xv = *reinterpret_cast<const ushort2*>(attn_io + base + 2 * lane);
  float x0 = bf2f(xv.x), x1 = bf2f(xv.y);
  float ss = x0 * x0 + x1 * x1;
#pragma unroll
  for (int off = 32; off > 0; off >>= 1) ss += __shfl_xor(ss, off, 64);
  float inv = rsqrtf(ss * (1.f / 128.f) + 1e-6f);
  const int p0 = h * Kc + 2 * lane;
  ushort2 gv = *reinterpret_cast<const ushort2*>(gate_raw + row * Pc + p0);
  float g0 = bf2f(gv.x) + bgb[p0];
  float g1 = bf2f(gv.y) + bgb[p0 + 1];
  float o0 = x0 * inv * o_norm_w[2 * lane] * fsig(g0);
  float o1 = x1 * inv * o_norm_w[2 * lane + 1] * fsig(g1);
  ushort2 ov; ov.x = f2bf(o0); ov.y = f2bf(o1);
  *reinterpret_cast<ushort2*>(attn_io + base + 2 * lane) = ov;
}

// ---------------- launch ----------------
extern "C" void kernel_launch(void* const* d_in, const int* in_sizes, int n_in,
                              void* d_out, int out_size, void* d_ws, size_t ws_size,
                              hipStream_t stream) {
  (void)in_sizes; (void)n_in;
  const float* x        = (const float*)d_in[0];
  const float* Wq       = (const float*)d_in[1];
  const float* Wk       = (const float*)d_in[2];
  const float* Wv       = (const float*)d_in[3];
  const float* conv_q   = (const float*)d_in[4];
  const float* conv_k   = (const float*)d_in[5];
  const float* conv_v   = (const float*)d_in[6];
  const float* A_log    = (const float*)d_in[7];
  const float* dt_bias  = (const float*)d_in[8];
  const float* Wfa      = (const float*)d_in[9];
  const float* Wfb      = (const float*)d_in[10];
  const float* Wb       = (const float*)d_in[11];
  const float* Wga      = (const float*)d_in[12];
  const float* Wgb      = (const float*)d_in[13];
  const float* bgb      = (const float*)d_in[14];
  const float* o_norm_w = (const float*)d_in[15];
  const float* Wo       = (const float*)d_in[16];
  const float* snap_nw  = (const float*)d_in[17];
  const float* snap_down= (const float*)d_in[18];

  const size_t MP2 = (size_t)Mc * Pc * 2;
  const size_t NEED = 6 * MP2
                    + 2 * (size_t)Mc * Kc * 4
                    + (size_t)Mc * Hc * 4
                    + (size_t)Bc * Hc * NCc * Kc * 4;
  if (ws_size < NEED + 4096) {
    hipMemsetAsync(d_out, 0, (size_t)out_size * 4, stream);
    return;
  }
  char* w = (char*)d_ws;
  auto alloc = [&](size_t bytes) {
    char* r = w;
    w += (bytes + 255) & ~(size_t)255;
    return r;
  };
  unsigned short* q_lin = (unsigned short*)alloc(MP2);  // q,k,v contiguous (QKV-fused out)
  unsigned short* k_lin = (unsigned short*)alloc(MP2);
  unsigned short* v_lin = (unsigned short*)alloc(MP2);
  unsigned short* g_raw = (unsigned short*)alloc(MP2);
  unsigned short* evb   = (unsigned short*)alloc(MP2);
  unsigned short* ewb   = (unsigned short*)alloc(MP2);
  float* fa    = (float*)alloc((size_t)Mc * Kc * 4);    // fab + betabb (bf16)
  float* ga    = (float*)alloc((size_t)Mc * Kc * 4);
  float* betab = (float*)alloc((size_t)Mc * Hc * 4);    // unused (kept for NEED layout)
  float* wlast = (float*)alloc((size_t)Bc * Hc * NCc * Kc * 4);
  (void)betab;

  unsigned short* qt = (unsigned short*)d_out;
  unsigned short* u_ = (unsigned short*)((char*)d_out + MP2);

  unsigned short* xb    = evb;
  unsigned short* Wqb   = ewb;                 // [Wq;Wk;Wv] contiguous (6144 rows)
  unsigned short* Wkb   = ewb + 4194304;
  unsigned short* Wvb   = ewb + 8388608;
  unsigned short* Wfab  = ewb + 12582912;      // [Wfa;Wga;Wb_pad] contiguous (384 rows)
  unsigned short* Wgab  = ewb + 12845056;
  unsigned short* Wbp   = ewb + 13107200;      // padded Wb: 128x2048 bf16
  unsigned short* Wfbb  = ewb + 13369344;      // ends 13,631,488 < 16,777,216
  unsigned short* fab   = (unsigned short*)fa;              // 8192x128 bf16
  unsigned short* betabb= (unsigned short*)fa + 1048576;    // 8192x128 bf16 (exact fit)
  unsigned short* gab   = (unsigned short*)ga;

  unsigned short* intra = q_lin;
  unsigned short* Wob   = q_lin + 8388608;
  unsigned short* Wgbb  = q_lin + 12582912;
  unsigned short* attn  = k_lin;
  unsigned short* gate_raw = g_raw;
  unsigned short* snapb = v_lin;
  unsigned short* sdwb  = v_lin + (size_t)512 * 16384;
  float* partial   = (float*)ewb;
  float* snapscale = (float*)(ewb + 4400000);

  float* y = (float*)d_out;
  float* snaps_out = (float*)d_out + (size_t)Bc * Tc * Dc;

  // 0) casts (+ zero-padded Wb)
  cast_f32_bf16<<<16384, 256, 0, stream>>>(x, xb, Mc * Dc);
  cast_f32_bf16<<<4096, 256, 0, stream>>>(Wq, Wqb, Pc * Dc);
  cast_f32_bf16<<<4096, 256, 0, stream>>>(Wk, Wkb, Pc * Dc);
  cast_f32_bf16<<<4096, 256, 0, stream>>>(Wv, Wvb, Pc * Dc);
  cast_f32_bf16<<<256, 256, 0, stream>>>(Wfa, Wfab, Kc * Dc);
  cast_f32_bf16<<<256, 256, 0, stream>>>(Wga, Wgab, Kc * Dc);
  hipMemsetAsync(Wbp, 0, (size_t)128 * 2048 * 2, stream);
  cast_f32_bf16<<<32, 256, 0, stream>>>(Wb, Wbp, Hc * Dc);  // rows 0..15 valid
  cast_f32_bf16<<<256, 256, 0, stream>>>(Wfb, Wfbb, Pc * Kc);

  // 1) input GEMMs (bf16 MFMA): 2-wave QKV + fused fa/ga/beta + g_raw
  gemm_nt_mfma_qkv2<<<dim3(64, 48), 128, 0, stream>>>(xb, Wqb, q_lin, Dc);
  gemm_nt_mfma_fgb<<<dim3(64, 3), 256, 0, stream>>>(xb, Wfab, fab, gab, betabb, Dc);
  gemm_nt_mfma2<unsigned short><<<dim3(64, 16), 128, 0, stream>>>(fab, Wfbb, g_raw, Pc, Kc);

  // 2) chunk prep (wave-per-chunk; beta bf16 stride 128)
  chunk_prep<<<Bc * Hc * NCc / 4, 256, 0, stream>>>(q_lin, k_lin, v_lin, g_raw, betabb, conv_q,
                                                    conv_k, conv_v, A_log, dt_bias, qt, u_, evb,
                                                    ewb, wlast);

  // 3) late casts into q_lin's dead tail
  cast_f32_bf16<<<4096, 256, 0, stream>>>(Wo, Wob, Dc * Pc);
  cast_f32_bf16<<<256, 256, 0, stream>>>(Wgb, Wgbb, Pc * Kc);

  // chunk solve (also transposes u -> uT in place)
  chunk_solve_mfma<<<Bc * Hc * NCc, 256, 0, stream>>>(qt, u_, evb, ewb, intra);

  // 4) gate projection
  gemm_nt_mfma2<unsigned short><<<dim3(64, 16), 128, 0, stream>>>(gab, Wgbb, gate_raw, Pc, Kc);

  // 5) MFMA scan, v-split x4 (u_ holds uT)
  scan_mfma<<<Bc * Hc * 4, 512, 0, stream>>>(qt, u_, evb, ewb, intra, wlast, attn, snapb);

  // 6) snapshots
  sdw_mul_bf16<<<2048, 256, 0, stream>>>(snap_down, snap_nw, sdwb);
  snap_scale_kernel<<<512, 256, 0, stream>>>(snapb, snapscale);
  gemm_nt_mfma_sk<<<dim3(4, 1, 16), 256, 0, stream>>>(snapb, sdwb, partial, 128, 16384, 1024, 512);
  snap_reduce_scatter<<<256, 256, 0, stream>>>(partial, snapscale, snaps_out);

  // 7) output norm*gate + final projection
  out_norm_gate<<<Mc * Hc / 4, 256, 0, stream>>>(attn, gate_raw, bgb, o_norm_w);
  gemm_nt_mfma2<float><<<dim3(64, 16), 128, 0, stream>>>(attn, Wob, y, Dc, Pc);
}

// Round 18
// 856.572 us; speedup vs baseline: 1.1151x; 1.1151x over previous
//
#include <hip/hip_runtime.h>

// ---------------- problem constants ----------------
constexpr int Bc   = 2;
constexpr int Tc   = 4096;
constexpr int Dc   = 2048;
constexpr int Hc   = 16;
constexpr int Kc   = 128;
constexpr int Pc   = Hc * Kc;     // 2048
constexpr int Cc   = 64;          // chunk size
constexpr int NCc  = Tc / Cc;     // 64 chunks
constexpr int Mc   = Bc * Tc;     // 8192 rows
constexpr int LATc = 128;

// ---------------- helpers ----------------
__device__ __forceinline__ float bf2f(unsigned short u) {
  unsigned int x = ((unsigned int)u) << 16;
  return __builtin_bit_cast(float, x);
}
__device__ __forceinline__ unsigned short f2bf(float f) {
  unsigned int x = __builtin_bit_cast(unsigned int, f);
  x += 0x7fffu + ((x >> 16) & 1u);
  return (unsigned short)(x >> 16);
}
__device__ __forceinline__ float4 ld4(const float* p) {
  return *reinterpret_cast<const float4*>(p);
}
__device__ __forceinline__ float4 ld4(const unsigned short* p) {
  ushort4 u = *reinterpret_cast<const ushort4*>(p);
  return make_float4(bf2f(u.x), bf2f(u.y), bf2f(u.z), bf2f(u.w));
}
__device__ __forceinline__ void st1(float* p, float v) { *p = v; }
__device__ __forceinline__ void st1(unsigned short* p, float v) { *p = f2bf(v); }

// fast transcendentals (native v_exp_f32 / v_log_f32 / v_rcp_f32)
__device__ __forceinline__ float fsig(float x) {
  return __fdividef(1.f, 1.f + __expf(-x));
}
__device__ __forceinline__ float fsoftplus(float g) {
  return (g > 20.f) ? g : __logf(1.f + __expf(g));
}

typedef __attribute__((ext_vector_type(8))) short bf16x8;
typedef __attribute__((ext_vector_type(4))) float f32x4;

// LDS swizzles: rows of stride 256B (swzA), 128B (swzB), 64B (swzC)
__device__ __forceinline__ int swzA(int row, int kbyte) { return row * 256 + (kbyte ^ ((row & 7) << 4)); }
__device__ __forceinline__ int swzB(int row, int kbyte) { return row * 128 + (kbyte ^ ((row & 7) << 4)); }
__device__ __forceinline__ int swzC(int row, int kbyte) { return row * 64 + (kbyte ^ (((row >> 2) & 3) << 4)); }
__device__ __forceinline__ bf16x8 ldsv8(const unsigned short* base, int byteoff) {
  return *reinterpret_cast<const bf16x8*>(reinterpret_cast<const char*>(base) + byteoff);
}
__device__ __forceinline__ void stsv16B(unsigned short* base, int byteoff, int4 v) {
  *reinterpret_cast<int4*>(reinterpret_cast<char*>(base) + byteoff) = v;
}
__device__ __forceinline__ void stsv8B(unsigned short* base, int byteoff, uint2 v) {
  *reinterpret_cast<uint2*>(reinterpret_cast<char*>(base) + byteoff) = v;
}
__device__ __forceinline__ unsigned short lds16(const unsigned short* base, int byteoff) {
  return *reinterpret_cast<const unsigned short*>(reinterpret_cast<const char*>(base) + byteoff);
}

// bijective XCD-aware block swizzle (T1); identity unless nwg%8==0 && nwg>=16
__device__ __forceinline__ int xcd_swz(int id, int nwg) {
  if ((nwg & 7) != 0 || nwg < 16) return id;
  return (id & 7) * (nwg >> 3) + (id >> 3);
}

// ---------------- f32 -> bf16 cast ----------------
__global__ void cast_f32_bf16(const float* __restrict__ in, unsigned short* __restrict__ out,
                              int n) {
  int i = (blockIdx.x * 256 + threadIdx.x) * 4;
  if (i < n) {
    float4 v = ld4(in + i);
    ushort4 o;
    o.x = f2bf(v.x); o.y = f2bf(v.y); o.z = f2bf(v.z); o.w = f2bf(v.w);
    *reinterpret_cast<ushort4*>(out + i) = o;
  }
}

// ---------------- bf16 MFMA NT GEMM (128x128 tile, m97 structure) ------
// XCD swizzle + GROUP_M=8 raster; k-group permutation (kg ^= (row>>1)&3) for
// conflict-free ds_read_b128 fragment reads (rule #21).
__device__ __forceinline__ void gload_lds16(const unsigned short* g, unsigned short* l) {
  __builtin_amdgcn_global_load_lds(
      (const __attribute__((address_space(1))) void*)g,
      (__attribute__((address_space(3))) void*)l, 16, 0, 0);
}

__device__ __forceinline__ void tile_map(int& m0, int& n0) {
  int id = blockIdx.y * gridDim.x + blockIdx.x;
  id = xcd_swz(id, gridDim.x * gridDim.y);
  const int bpg = gridDim.y << 3;     // 8 m-tiles per group
  int grp = id / bpg, rem = id % bpg;
  m0 = ((grp << 3) + (rem & 7)) * 128;
  n0 = (rem >> 3) * 128;
}

template <typename OT>
__global__ __launch_bounds__(256) void gemm_nt_mfma(const unsigned short* __restrict__ A,
                                                    const unsigned short* __restrict__ Bm,
                                                    OT* __restrict__ Out,
                                                    int Ndim, int Kd) {
  __shared__ __align__(16) unsigned short As[128 * 32];
  __shared__ __align__(16) unsigned short Bs[128 * 32];
  int m0, n0;
  tile_map(m0, n0);
  const int tid = threadIdx.x;
  const int wave = tid >> 6;
  const int lane = tid & 63;
  const int wr = wave >> 1, wc = wave & 1;
  const int l15 = lane & 15, l4 = lane >> 4;
  const int kxor = (l4 ^ ((l15 >> 1) & 3)) << 3;
  f32x4 acc[4][4] = {};

  for (int k0 = 0; k0 < Kd; k0 += 32) {
#pragma unroll
    for (int i = 0; i < 2; ++i) {
      int slot = (wave * 2 + i) * 64 + lane;
      int r = slot >> 2;
      int kg = (slot & 3) ^ ((r >> 1) & 3);
      gload_lds16(&A[(size_t)(m0 + r) * Kd + k0 + kg * 8], &As[(wave * 2 + i) * 512]);
      gload_lds16(&Bm[(size_t)(n0 + r) * Kd + k0 + kg * 8], &Bs[(wave * 2 + i) * 512]);
    }
    __syncthreads();
    bf16x8 af[4], bfr[4];
#pragma unroll
    for (int m = 0; m < 4; ++m)
      af[m] = *reinterpret_cast<const bf16x8*>(&As[(wr * 64 + m * 16 + l15) * 32 + kxor]);
#pragma unroll
    for (int n = 0; n < 4; ++n)
      bfr[n] = *reinterpret_cast<const bf16x8*>(&Bs[(wc * 64 + n * 16 + l15) * 32 + kxor]);
#pragma unroll
    for (int m = 0; m < 4; ++m)
#pragma unroll
      for (int n = 0; n < 4; ++n)
        acc[m][n] = __builtin_amdgcn_mfma_f32_16x16x32_bf16(af[m], bfr[n], acc[m][n], 0, 0, 0);
    __syncthreads();
  }
#pragma unroll
  for (int m = 0; m < 4; ++m)
#pragma unroll
    for (int n = 0; n < 4; ++n)
#pragma unroll
      for (int r = 0; r < 4; ++r) {
        int row = m0 + wr * 64 + m * 16 + l4 * 4 + r;
        int col = n0 + wc * 64 + n * 16 + l15;
        st1(&Out[(size_t)row * Ndim + col], acc[m][n][r]);
      }
}

// ---- fused QKV variant ----
__global__ __launch_bounds__(256) void gemm_nt_mfma_qkv(const unsigned short* __restrict__ A,
                                                        const unsigned short* __restrict__ Bm,
                                                        unsigned short* __restrict__ Out,
                                                        int Kd) {
  __shared__ __align__(16) unsigned short As[128 * 32];
  __shared__ __align__(16) unsigned short Bs[128 * 32];
  int m0, n0;
  tile_map(m0, n0);
  const int tid = threadIdx.x;
  const int wave = tid >> 6;
  const int lane = tid & 63;
  const int wr = wave >> 1, wc = wave & 1;
  const int l15 = lane & 15, l4 = lane >> 4;
  const int kxor = (l4 ^ ((l15 >> 1) & 3)) << 3;
  f32x4 acc[4][4] = {};

  for (int k0 = 0; k0 < Kd; k0 += 32) {
#pragma unroll
    for (int i = 0; i < 2; ++i) {
      int slot = (wave * 2 + i) * 64 + lane;
      int r = slot >> 2;
      int kg = (slot & 3) ^ ((r >> 1) & 3);
      gload_lds16(&A[(size_t)(m0 + r) * Kd + k0 + kg * 8], &As[(wave * 2 + i) * 512]);
      gload_lds16(&Bm[(size_t)(n0 + r) * Kd + k0 + kg * 8], &Bs[(wave * 2 + i) * 512]);
    }
    __syncthreads();
    bf16x8 af[4], bfr[4];
#pragma unroll
    for (int m = 0; m < 4; ++m)
      af[m] = *reinterpret_cast<const bf16x8*>(&As[(wr * 64 + m * 16 + l15) * 32 + kxor]);
#pragma unroll
    for (int n = 0; n < 4; ++n)
      bfr[n] = *reinterpret_cast<const bf16x8*>(&Bs[(wc * 64 + n * 16 + l15) * 32 + kxor]);
#pragma unroll
    for (int m = 0; m < 4; ++m)
#pragma unroll
      for (int n = 0; n < 4; ++n)
        acc[m][n] = __builtin_amdgcn_mfma_f32_16x16x32_bf16(af[m], bfr[n], acc[m][n], 0, 0, 0);
    __syncthreads();
  }
  unsigned short* dst = Out + (size_t)(n0 >> 11) * ((size_t)Mc * 2048);
  const int cbase = n0 & 2047;
#pragma unroll
  for (int m = 0; m < 4; ++m)
#pragma unroll
    for (int n = 0; n < 4; ++n)
#pragma unroll
      for (int r = 0; r < 4; ++r) {
        int row = m0 + wr * 64 + m * 16 + l4 * 4 + r;
        int col = cbase + wc * 64 + n * 16 + l15;
        dst[(size_t)row * 2048 + col] = f2bf(acc[m][n][r]);
      }
}

// ---- fused fa/ga/beta variant: B = [Wfa;Wga;Wb_pad] (384 rows); grid (64,3).
__global__ __launch_bounds__(256) void gemm_nt_mfma_fgb(const unsigned short* __restrict__ A,
                                                        const unsigned short* __restrict__ Bm,
                                                        unsigned short* __restrict__ fab,
                                                        unsigned short* __restrict__ gab,
                                                        unsigned short* __restrict__ betabb,
                                                        int Kd) {
  __shared__ __align__(16) unsigned short As[128 * 32];
  __shared__ __align__(16) unsigned short Bs[128 * 32];
  int m0, n0;
  tile_map(m0, n0);
  const int tid = threadIdx.x;
  const int wave = tid >> 6;
  const int lane = tid & 63;
  const int wr = wave >> 1, wc = wave & 1;
  const int l15 = lane & 15, l4 = lane >> 4;
  const int kxor = (l4 ^ ((l15 >> 1) & 3)) << 3;
  f32x4 acc[4][4] = {};

  for (int k0 = 0; k0 < Kd; k0 += 32) {
#pragma unroll
    for (int i = 0; i < 2; ++i) {
      int slot = (wave * 2 + i) * 64 + lane;
      int r = slot >> 2;
      int kg = (slot & 3) ^ ((r >> 1) & 3);
      gload_lds16(&A[(size_t)(m0 + r) * Kd + k0 + kg * 8], &As[(wave * 2 + i) * 512]);
      gload_lds16(&Bm[(size_t)(n0 + r) * Kd + k0 + kg * 8], &Bs[(wave * 2 + i) * 512]);
    }
    __syncthreads();
    bf16x8 af[4], bfr[4];
#pragma unroll
    for (int m = 0; m < 4; ++m)
      af[m] = *reinterpret_cast<const bf16x8*>(&As[(wr * 64 + m * 16 + l15) * 32 + kxor]);
#pragma unroll
    for (int n = 0; n < 4; ++n)
      bfr[n] = *reinterpret_cast<const bf16x8*>(&Bs[(wc * 64 + n * 16 + l15) * 32 + kxor]);
#pragma unroll
    for (int m = 0; m < 4; ++m)
#pragma unroll
      for (int n = 0; n < 4; ++n)
        acc[m][n] = __builtin_amdgcn_mfma_f32_16x16x32_bf16(af[m], bfr[n], acc[m][n], 0, 0, 0);
    __syncthreads();
  }
  unsigned short* dst = (n0 == 0) ? fab : ((n0 == 128) ? gab : betabb);
#pragma unroll
  for (int m = 0; m < 4; ++m)
#pragma unroll
    for (int n = 0; n < 4; ++n)
#pragma unroll
      for (int r = 0; r < 4; ++r) {
        int row = m0 + wr * 64 + m * 16 + l4 * 4 + r;
        int lc = wc * 64 + n * 16 + l15;
        dst[(size_t)row * 128 + lc] = f2bf(acc[m][n][r]);
      }
}

// ---- splitK variant ----
__global__ __launch_bounds__(256) void gemm_nt_mfma_sk(const unsigned short* __restrict__ A,
                                                       const unsigned short* __restrict__ Bm,
                                                       float* __restrict__ Part,
                                                       int Ndim, int Kd, int kslice, int Mtot) {
  __shared__ __align__(16) unsigned short As[128 * 32];
  __shared__ __align__(16) unsigned short Bs[128 * 32];
  const int m0 = blockIdx.x * 128;
  const int n0 = blockIdx.y * 128;
  const int kz = blockIdx.z * kslice;
  const int tid = threadIdx.x;
  const int wave = tid >> 6;
  const int lane = tid & 63;
  const int wr = wave >> 1, wc = wave & 1;
  const int l15 = lane & 15, l4 = lane >> 4;
  const int kxor = (l4 ^ ((l15 >> 1) & 3)) << 3;
  f32x4 acc[4][4] = {};

  for (int k0 = kz; k0 < kz + kslice; k0 += 32) {
#pragma unroll
    for (int i = 0; i < 2; ++i) {
      int slot = (wave * 2 + i) * 64 + lane;
      int r = slot >> 2;
      int kg = (slot & 3) ^ ((r >> 1) & 3);
      gload_lds16(&A[(size_t)(m0 + r) * Kd + k0 + kg * 8], &As[(wave * 2 + i) * 512]);
      gload_lds16(&Bm[(size_t)(n0 + r) * Kd + k0 + kg * 8], &Bs[(wave * 2 + i) * 512]);
    }
    __syncthreads();
    bf16x8 af[4], bfr[4];
#pragma unroll
    for (int m = 0; m < 4; ++m)
      af[m] = *reinterpret_cast<const bf16x8*>(&As[(wr * 64 + m * 16 + l15) * 32 + kxor]);
#pragma unroll
    for (int n = 0; n < 4; ++n)
      bfr[n] = *reinterpret_cast<const bf16x8*>(&Bs[(wc * 64 + n * 16 + l15) * 32 + kxor]);
#pragma unroll
    for (int m = 0; m < 4; ++m)
#pragma unroll
      for (int n = 0; n < 4; ++n)
        acc[m][n] = __builtin_amdgcn_mfma_f32_16x16x32_bf16(af[m], bfr[n], acc[m][n], 0, 0, 0);
    __syncthreads();
  }
  float* out = Part + (size_t)blockIdx.z * Mtot * Ndim;
#pragma unroll
  for (int m = 0; m < 4; ++m)
#pragma unroll
    for (int n = 0; n < 4; ++n)
#pragma unroll
      for (int r = 0; r < 4; ++r) {
        int row = m0 + wr * 64 + m * 16 + l4 * 4 + r;
        int col = n0 + wc * 64 + n * 16 + l15;
        out[(size_t)row * Ndim + col] = acc[m][n][r];
      }
}

// ---------------- chunk prep: one WAVE per chunk ----------------
// grid: Bc*Hc*NCc/4 = 512 blocks x 256 threads (4 waves = 4 chunks)
__global__ __launch_bounds__(256) void chunk_prep(
    const unsigned short* __restrict__ q_lin, const unsigned short* __restrict__ k_lin,
    const unsigned short* __restrict__ v_lin, const unsigned short* __restrict__ g_raw,
    const unsigned short* __restrict__ beta16, const float* __restrict__ conv_q,
    const float* __restrict__ conv_k, const float* __restrict__ conv_v,
    const float* __restrict__ A_log, const float* __restrict__ dt_bias,
    unsigned short* __restrict__ qt, unsigned short* __restrict__ u_,
    unsigned short* __restrict__ bv, unsigned short* __restrict__ bw,
    float* __restrict__ wlast) {
  const int wave = threadIdx.x >> 6, lane = threadIdx.x & 63;
  const int cid = blockIdx.x * 4 + wave;  // (b*H+h)*NC + n
  const int n = cid & 63;
  const int h = (cid >> 6) & 15;
  const int b = cid >> 10;
  const int k0 = 2 * lane;
  const int p = h * Kc + k0;
  float cq[2][4], ck[2][4], cv[2][4];
#pragma unroll
  for (int s = 0; s < 2; ++s)
#pragma unroll
    for (int j = 0; j < 4; ++j) {
      cq[s][j] = conv_q[(p + s) * 4 + j];
      ck[s][j] = conv_k[(p + s) * 4 + j];
      cv[s][j] = conv_v[(p + s) * 4 + j];
    }
  const float aneg = -__expf(A_log[h]);
  const float db0 = dt_bias[p], db1 = dt_bias[p + 1];
  float cum0 = 0.f, cum1 = 0.f;
  const int t0 = n * Cc;
  float wq[2][3] = {}, wk[2][3] = {}, wv[2][3] = {};
#pragma unroll
  for (int d = 0; d < 3; ++d) {
    int ts = t0 - 3 + d;
    if (ts >= 0) {
      size_t o = ((size_t)(b * Tc + ts)) * Pc + p;
      ushort2 q2 = *(const ushort2*)(q_lin + o);
      ushort2 k2 = *(const ushort2*)(k_lin + o);
      ushort2 v2 = *(const ushort2*)(v_lin + o);
      wq[0][d] = bf2f(q2.x); wq[1][d] = bf2f(q2.y);
      wk[0][d] = bf2f(k2.x); wk[1][d] = bf2f(k2.y);
      wv[0][d] = bf2f(v2.x); wv[1][d] = bf2f(v2.y);
    }
  }
  for (int c = 0; c < Cc; ++c) {
    const int t = t0 + c;
    size_t off = ((size_t)(b * Tc + t)) * Pc + p;
    ushort2 q2 = *(const ushort2*)(q_lin + off);
    ushort2 k2 = *(const ushort2*)(k_lin + off);
    ushort2 v2 = *(const ushort2*)(v_lin + off);
    ushort2 g2 = *(const ushort2*)(g_raw + off);
    float nq[2] = {bf2f(q2.x), bf2f(q2.y)};
    float nk[2] = {bf2f(k2.x), bf2f(k2.y)};
    float nv[2] = {bf2f(v2.x), bf2f(v2.y)};
    float qv[2], kv[2], vv[2];
#pragma unroll
    for (int s = 0; s < 2; ++s) {
      qv[s] = cq[s][0] * wq[s][0] + cq[s][1] * wq[s][1] + cq[s][2] * wq[s][2] + cq[s][3] * nq[s];
      kv[s] = ck[s][0] * wk[s][0] + ck[s][1] * wk[s][1] + ck[s][2] * wk[s][2] + ck[s][3] * nk[s];
      vv[s] = cv[s][0] * wv[s][0] + cv[s][1] * wv[s][1] + cv[s][2] * wv[s][2] + cv[s][3] * nv[s];
      wq[s][0] = wq[s][1]; wq[s][1] = wq[s][2]; wq[s][2] = nq[s];
      wk[s][0] = wk[s][1]; wk[s][1] = wk[s][2]; wk[s][2] = nk[s];
      wv[s][0] = wv[s][1]; wv[s][1] = wv[s][2]; wv[s][2] = nv[s];
      qv[s] = qv[s] * fsig(qv[s]);  // silu
      kv[s] = kv[s] * fsig(kv[s]);
      vv[s] = vv[s] * fsig(vv[s]);
    }
    float a = qv[0] * qv[0] + qv[1] * qv[1];
    float bb = kv[0] * kv[0] + kv[1] * kv[1];
#pragma unroll
    for (int off2 = 32; off2 > 0; off2 >>= 1) {
      a += __shfl_xor(a, off2, 64);
      bb += __shfl_xor(bb, off2, 64);
    }
    float rq = rsqrtf(a + 1e-12f) * 0.08838834764831845f;  // * K^-0.5
    float rk = rsqrtf(bb + 1e-12f);
    float g0 = bf2f(g2.x) + db0, g1 = bf2f(g2.y) + db1;
    cum0 += aneg * fsoftplus(g0);
    cum1 += aneg * fsoftplus(g1);
    float cc0 = fmaxf(cum0, -15.f), cc1 = fmaxf(cum1, -15.f);
    float Wg0 = __expf(cc0), Wg1 = __expf(cc1);
    float Wi0 = __fdividef(1.f, Wg0), Wi1 = __fdividef(1.f, Wg1);
    float beta = fsig(bf2f(beta16[((size_t)(b * Tc + t)) * 128 + h]));
    size_t idx = ((size_t)cid * Cc + c) * Kc + k0;
    ushort2 o1, o2, o3, o4;
    o1.x = f2bf(qv[0] * rq * Wg0); o1.y = f2bf(qv[1] * rq * Wg1);
    o2.x = f2bf(kv[0] * rk * Wi0); o2.y = f2bf(kv[1] * rk * Wi1);
    o3.x = f2bf(beta * kv[0] * rk * Wg0); o3.y = f2bf(beta * kv[1] * rk * Wg1);
    o4.x = f2bf(beta * vv[0]); o4.y = f2bf(beta * vv[1]);
    *(ushort2*)(qt + idx) = o1;
    *(ushort2*)(u_ + idx) = o2;
    *(ushort2*)(bw + idx) = o3;
    *(ushort2*)(bv + idx) = o4;
    if (c == Cc - 1) {
      wlast[(size_t)cid * Kc + k0] = Wg0;
      wlast[(size_t)cid * Kc + k0 + 1] = Wg1;
    }
  }
}

// ---------------- MFMA chunk solve + in-place u -> u^T transpose ----------------
__global__ __launch_bounds__(256) void chunk_solve_mfma(
    const unsigned short* __restrict__ qt, unsigned short* __restrict__ u_,
    unsigned short* __restrict__ evb,  // in: bv, out: ev
    unsigned short* __restrict__ ewb,  // in: bw, out: ew
    unsigned short* __restrict__ intra_out) {
  const int blk = blockIdx.x;
  const size_t base = (size_t)blk * (Cc * Kc);
  const size_t ibase = (size_t)blk * (Cc * Cc);
  const int tid = threadIdx.x, wave = tid >> 6, lane = tid & 63;
  const int l15 = lane & 15, l4 = lane >> 4;

  __shared__ __align__(16) char lds[65536];
  unsigned short* uS   = (unsigned short*)(lds);            // [64][128] swzA
  unsigned short* qtS  = (unsigned short*)(lds + 16384);    // [64][128] swzA
  unsigned short* bwS  = (unsigned short*)(lds + 32768);    // [64][128] swzA
  unsigned short* NLrm = (unsigned short*)(lds + 49152);    // [64][64] swzB
  unsigned short* NLT  = (unsigned short*)(lds + 57344);    // [64][64] swzB
  unsigned short* Trm  = (unsigned short*)(lds);            // over uS
  unsigned short* TT   = (unsigned short*)(lds + 8192);
  unsigned short* Prm  = (unsigned short*)(lds + 16384);    // over qtS
  unsigned short* PT   = (unsigned short*)(lds + 24576);
  unsigned short* bvT  = (unsigned short*)(lds + 32768);    // [128][64] swzB, over bwS
  unsigned short* bwT  = (unsigned short*)(lds + 49152);    // [128][64] swzB, over NL

#pragma unroll
  for (int i = 0; i < 4; ++i) {
    int cid = tid + i * 256;
    int r = cid >> 4, c8 = (cid & 15) * 8, cb2 = (cid & 15) * 16;
    int4 vu = *(const int4*)(u_ + base + (size_t)r * 128 + c8);
    int4 vb = *(const int4*)(ewb + base + (size_t)r * 128 + c8);
    int4 vq = *(const int4*)(qt + base + (size_t)r * 128 + c8);
    stsv16B(uS, swzA(r, cb2), vu);
    stsv16B(bwS, swzA(r, cb2), vb);
    stsv16B(qtS, swzA(r, cb2), vq);
  }
  __syncthreads();

  const int arow = 16 * wave + l15;
  bf16x8 aBw[4], aQt[4];
#pragma unroll
  for (int ks = 0; ks < 4; ++ks) {
    aBw[ks] = ldsv8(bwS, swzA(arow, 16 * l4 + 64 * ks));
    aQt[ks] = ldsv8(qtS, swzA(arow, 16 * l4 + 64 * ks));
  }
  f32x4 Lc[4], Ic[4];
#pragma unroll
  for (int nt = 0; nt < 4; ++nt) {
    f32x4 a = {}, bq = {};
#pragma unroll
    for (int ks = 0; ks < 4; ++ks) {
      bf16x8 bu = ldsv8(uS, swzA(16 * nt + l15, 16 * l4 + 64 * ks));
      a = __builtin_amdgcn_mfma_f32_16x16x32_bf16(aBw[ks], bu, a, 0, 0, 0);
      bq = __builtin_amdgcn_mfma_f32_16x16x32_bf16(aQt[ks], bu, bq, 0, 0, 0);
    }
    Lc[nt] = a; Ic[nt] = bq;
  }
#pragma unroll
  for (int nt = 0; nt < 4; ++nt)
#pragma unroll
    for (int r = 0; r < 4; ++r) {
      int row = 16 * wave + 4 * l4 + r, col = 16 * nt + l15;
      intra_out[ibase + (size_t)row * 64 + col] = f2bf((col <= row) ? Ic[nt][r] : 0.f);
    }

  // in-place u^T write-back
#pragma unroll
  for (int i = 0; i < 4; ++i) {
    int w2 = tid + i * 256;
    int k = w2 >> 3, cg = w2 & 7;
    unsigned short tmp[8];
#pragma unroll
    for (int j = 0; j < 8; ++j) {
      int c = cg + 8 * j;
      tmp[j] = lds16(uS, swzA(c, 2 * k));
    }
#pragma unroll
    for (int j = 0; j < 8; ++j)
      u_[base + (size_t)k * 64 + cg + 8 * j] = tmp[j];
  }
  __syncthreads();

  f32x4 Tf[4];
#pragma unroll
  for (int nt = 0; nt < 4; ++nt)
#pragma unroll
    for (int r = 0; r < 4; ++r) {
      int row = 16 * wave + 4 * l4 + r, col = 16 * nt + l15;
      float nl = (col < row) ? -Lc[nt][r] : 0.f;
      unsigned short nb = f2bf(nl);
      *reinterpret_cast<unsigned short*>((char*)NLrm + swzB(row, col * 2)) = nb;
      *reinterpret_cast<unsigned short*>((char*)NLT + swzB(col, row * 2)) = nb;
      float t0 = nl + ((row == col) ? 1.f : 0.f);
      Tf[nt][r] = t0;
      unsigned short tb = f2bf(t0);
      *reinterpret_cast<unsigned short*>((char*)Trm + swzB(row, col * 2)) = tb;
      *reinterpret_cast<unsigned short*>((char*)TT + swzB(col, row * 2)) = tb;
    }
  __syncthreads();

  bf16x8 aN[2];
#pragma unroll
  for (int ks = 0; ks < 2; ++ks) aN[ks] = ldsv8(NLrm, swzB(arow, 16 * l4 + 64 * ks));
  f32x4 Pf[4];
#pragma unroll
  for (int nt = 0; nt < 4; ++nt) {
    f32x4 acc = {};
#pragma unroll
    for (int ks = 0; ks < 2; ++ks)
      acc = __builtin_amdgcn_mfma_f32_16x16x32_bf16(aN[ks], ldsv8(NLT, swzB(16 * nt + l15, 16 * l4 + 64 * ks)), acc, 0, 0, 0);
    Pf[nt] = acc;
  }
  int4 rv[4], rw[4];
#pragma unroll
  for (int i = 0; i < 4; ++i) {
    int cid = tid + i * 256;
    int r = cid >> 4, c8 = (cid & 15) * 8;
    rv[i] = *(const int4*)(evb + base + (size_t)r * 128 + c8);
    rw[i] = *(const int4*)(ewb + base + (size_t)r * 128 + c8);
  }
#pragma unroll
  for (int nt = 0; nt < 4; ++nt)
#pragma unroll
    for (int r = 0; r < 4; ++r) {
      int row = 16 * wave + 4 * l4 + r, col = 16 * nt + l15;
      unsigned short pb = f2bf(Pf[nt][r]);
      *reinterpret_cast<unsigned short*>((char*)Prm + swzB(row, col * 2)) = pb;
      *reinterpret_cast<unsigned short*>((char*)PT + swzB(col, row * 2)) = pb;
    }
  __syncthreads();

  for (int it = 0; it < 5; ++it) {
    bf16x8 aP[2];
#pragma unroll
    for (int ks = 0; ks < 2; ++ks) aP[ks] = ldsv8(Prm, swzB(arow, 16 * l4 + 64 * ks));
    f32x4 Tn[4], Pn[4];
#pragma unroll
    for (int nt = 0; nt < 4; ++nt) {
      f32x4 acc = Tf[nt];
#pragma unroll
      for (int ks = 0; ks < 2; ++ks)
        acc = __builtin_amdgcn_mfma_f32_16x16x32_bf16(aP[ks], ldsv8(TT, swzB(16 * nt + l15, 16 * l4 + 64 * ks)), acc, 0, 0, 0);
      Tn[nt] = acc;
    }
    if (it < 4) {
#pragma unroll
      for (int nt = 0; nt < 4; ++nt) {
        f32x4 acc = {};
#pragma unroll
        for (int ks = 0; ks < 2; ++ks)
          acc = __builtin_amdgcn_mfma_f32_16x16x32_bf16(aP[ks], ldsv8(PT, swzB(16 * nt + l15, 16 * l4 + 64 * ks)), acc, 0, 0, 0);
        Pn[nt] = acc;
      }
    }
    __syncthreads();
#pragma unroll
    for (int nt = 0; nt < 4; ++nt)
#pragma unroll
      for (int r = 0; r < 4; ++r) {
        int row = 16 * wave + 4 * l4 + r, col = 16 * nt + l15;
        unsigned short tb = f2bf(Tn[nt][r]);
        *reinterpret_cast<unsigned short*>((char*)Trm + swzB(row, col * 2)) = tb;
        *reinterpret_cast<unsigned short*>((char*)TT + swzB(col, row * 2)) = tb;
        if (it < 4) {
          unsigned short pb = f2bf(Pn[nt][r]);
          *reinterpret_cast<unsigned short*>((char*)Prm + swzB(row, col * 2)) = pb;
          *reinterpret_cast<unsigned short*>((char*)PT + swzB(col, row * 2)) = pb;
        }
      }
#pragma unroll
    for (int nt = 0; nt < 4; ++nt) Tf[nt] = Tn[nt];
    __syncthreads();
  }

#pragma unroll
  for (int i = 0; i < 4; ++i) {
    int cid = tid + i * 256;
    int r = cid >> 4;
    const unsigned short* pv = reinterpret_cast<const unsigned short*>(&rv[i]);
    const unsigned short* pw = reinterpret_cast<const unsigned short*>(&rw[i]);
#pragma unroll
    for (int j = 0; j < 8; ++j) {
      int v = (cid & 15) * 8 + j;
      *reinterpret_cast<unsigned short*>((char*)bvT + swzB(v, r * 2)) = pv[j];
      *reinterpret_cast<unsigned short*>((char*)bwT + swzB(v, r * 2)) = pw[j];
    }
  }
  __syncthreads();

  bf16x8 aT[2];
#pragma unroll
  for (int ks = 0; ks < 2; ++ks) aT[ks] = ldsv8(Trm, swzB(arow, 16 * l4 + 64 * ks));
#pragma unroll
  for (int nt = 0; nt < 8; ++nt) {
    f32x4 e = {}, w2 = {};
#pragma unroll
    for (int ks = 0; ks < 2; ++ks) {
      e = __builtin_amdgcn_mfma_f32_16x16x32_bf16(aT[ks], ldsv8(bvT, swzB(16 * nt + l15, 16 * l4 + 64 * ks)), e, 0, 0, 0);
      w2 = __builtin_amdgcn_mfma_f32_16x16x32_bf16(aT[ks], ldsv8(bwT, swzB(16 * nt + l15, 16 * l4 + 64 * ks)), w2, 0, 0, 0);
    }
#pragma unroll
    for (int r = 0; r < 4; ++r) {
      int row = 16 * wave + 4 * l4 + r, col = 16 * nt + l15;
      evb[base + (size_t)row * 128 + col] = f2bf(e[r]);
      ewb[base + (size_t)row * 128 + col] = f2bf(w2[r]);
    }
  }
}

// ---------------- MFMA scan, v-split x4: grid = B*H*4, 8 waves --------------------
__global__ __launch_bounds__(512) void scan_mfma(
    const unsigned short* __restrict__ qt, const unsigned short* __restrict__ uT,
    const unsigned short* __restrict__ evb, const unsigned short* __restrict__ ewb,
    const unsigned short* __restrict__ intra, const float* __restrict__ wlast,
    unsigned short* __restrict__ attn_o, unsigned short* __restrict__ snapb) {
  const int id = xcd_swz(blockIdx.x, 128);
  const int bh = id >> 2, vs = id & 3;
  const int b = bh >> 4, h = bh & 15;
  const int v0 = vs * 32;
  const int tid = threadIdx.x, wave = tid >> 6, lane = tid & 63;
  const int l15 = lane & 15, l4 = lane >> 4;
  __shared__ __align__(16) unsigned short ewS[8192];  // [64 c][128 k] swzA
  __shared__ __align__(16) unsigned short qtS[8192];  // [64 c][128 k] swzA
  __shared__ __align__(16) unsigned short uTS[8192];  // [128 k][64 c] swzB
  __shared__ __align__(16) unsigned short iaS[4096];  // [64 c][64 j]  swzB
  __shared__ __align__(16) unsigned short evS[2048];  // [64 c][32 v]  swzC (slice)
  __shared__ __align__(16) unsigned short sBT[4096];  // [32 v][128 k] swzA (S^T slice)
  __shared__ __align__(16) unsigned short dBT[2048];  // [32 v][64 c]  swzB (delta^T)

  f32x4 S[2] = {};
  {
    int4 z = {0, 0, 0, 0};
    stsv16B(sBT, tid * 16, z);  // 512 thr x 16B = 8KB
  }

  const int sr = tid >> 3;           // 0..63
  const int sk0 = (tid & 7) * 16;    // 128-wide col base
  const int sc0 = (tid & 7) * 8;     // 64-wide col base
  const int evc = (tid & 7) * 4;     // 32-wide col base (4 els)
  const int tk = tid >> 3;           // uT rows tk, tk+64
  const int wloff = 16 * wave + 4 * l4;
  int4 rEw0, rEw1, rQt0, rQt1, rUT0, rUT1, rIa;
  uint2 rEv;
  float4 rWlN, rWlC;

#define STAGE_LOAD(CB, IB, NN)                                                    \
  rEw0 = *(const int4*)(ewb + (CB) + sr * 128 + sk0);                             \
  rEw1 = *(const int4*)(ewb + (CB) + sr * 128 + sk0 + 8);                         \
  rQt0 = *(const int4*)(qt + (CB) + sr * 128 + sk0);                              \
  rQt1 = *(const int4*)(qt + (CB) + sr * 128 + sk0 + 8);                          \
  rEv = *(const uint2*)(evb + (CB) + sr * 128 + v0 + evc);                        \
  rUT0 = *(const int4*)(uT + (CB) + (size_t)tk * 64 + sc0);                       \
  rUT1 = *(const int4*)(uT + (CB) + (size_t)(tk + 64) * 64 + sc0);                \
  rIa = *(const int4*)(intra + (IB) + sr * 64 + sc0);                             \
  rWlN = ld4(wlast + ((size_t)bh * 64 + (NN)) * 128 + wloff);

#define STAGE_WRITE()                                                             \
  stsv16B(ewS, swzA(sr, sk0 * 2), rEw0);                                          \
  stsv16B(ewS, swzA(sr, sk0 * 2 + 16), rEw1);                                     \
  stsv16B(qtS, swzA(sr, sk0 * 2), rQt0);                                          \
  stsv16B(qtS, swzA(sr, sk0 * 2 + 16), rQt1);                                     \
  stsv8B(evS, swzC(sr, evc * 2), rEv);                                            \
  stsv16B(iaS, swzB(sr, sc0 * 2), rIa);                                           \
  stsv16B(uTS, swzB(tk, sc0 * 2), rUT0);                                          \
  stsv16B(uTS, swzB(tk + 64, sc0 * 2), rUT1);

  {
    const size_t cb0 = (size_t)bh * 64 * 8192;
    const size_t ib0 = (size_t)bh * 64 * 4096;
    STAGE_LOAD(cb0, ib0, 0);
    STAGE_WRITE();
    rWlC = rWlN;
  }
  __syncthreads();

  const int m = wave & 3, vg = wave >> 2;    // wave's o-tile = (m, vg)
  const int arow = 16 * m + l15;
  const int krow = 16 * wave + l15;
  const int vl = 16 * vg + l15;              // wave's v column (local)

  for (int n = 0; n < NCc; ++n) {
    const size_t cb = ((size_t)bh * 64 + n) * 8192;
    const size_t ib = ((size_t)bh * 64 + n) * 4096;
    // ---- Phase A: prefetch n+1; delta = ev - ew@S -> dBT ----
    if (n < 63) { STAGE_LOAD(cb + 8192, ib + 4096, n + 1); }
    bf16x8 aEw[4];
#pragma unroll
    for (int ks = 0; ks < 4; ++ks) aEw[ks] = ldsv8(ewS, swzA(arow, 16 * l4 + 64 * ks));
    {
      f32x4 p = {};
#pragma unroll
      for (int ks = 0; ks < 4; ++ks)
        p = __builtin_amdgcn_mfma_f32_16x16x32_bf16(aEw[ks], ldsv8(sBT, swzA(vl, 16 * l4 + 64 * ks)), p, 0, 0, 0);
      float d[4];
#pragma unroll
      for (int r = 0; r < 4; ++r) {
        int c = 16 * m + 4 * l4 + r;
        d[r] = bf2f(lds16(evS, swzC(c, 2 * vl))) - p[r];
      }
      uint2 pk;
      pk.x = (unsigned)f2bf(d[0]) | ((unsigned)f2bf(d[1]) << 16);
      pk.y = (unsigned)f2bf(d[2]) | ((unsigned)f2bf(d[3]) << 16);
      stsv8B(dBT, swzB(vl, (16 * m + 4 * l4) * 2), pk);
    }
    __syncthreads();
    // ---- Phase B1: o = qt@S + ia@delta; S = wl*(S + uT@delta) ----
    bf16x8 aQt[4], aIa[2], aU[2];
#pragma unroll
    for (int ks = 0; ks < 4; ++ks) aQt[ks] = ldsv8(qtS, swzA(arow, 16 * l4 + 64 * ks));
#pragma unroll
    for (int ks = 0; ks < 2; ++ks) aIa[ks] = ldsv8(iaS, swzB(arow, 16 * l4 + 64 * ks));
#pragma unroll
    for (int ks = 0; ks < 2; ++ks) aU[ks] = ldsv8(uTS, swzB(krow, 16 * l4 + 64 * ks));
    {
      f32x4 o = {};
#pragma unroll
      for (int ks = 0; ks < 4; ++ks)
        o = __builtin_amdgcn_mfma_f32_16x16x32_bf16(aQt[ks], ldsv8(sBT, swzA(vl, 16 * l4 + 64 * ks)), o, 0, 0, 0);
#pragma unroll
      for (int ks = 0; ks < 2; ++ks)
        o = __builtin_amdgcn_mfma_f32_16x16x32_bf16(aIa[ks], ldsv8(dBT, swzB(vl, 16 * l4 + 64 * ks)), o, 0, 0, 0);
#pragma unroll
      for (int r = 0; r < 4; ++r) {
        int c = 16 * m + 4 * l4 + r;
        int t = n * 64 + c;
        attn_o[((size_t)(b * Tc + t) * Hc + h) * Kc + v0 + vl] = f2bf(o[r]);
      }
    }
    float wlv[4] = {rWlC.x, rWlC.y, rWlC.z, rWlC.w};
#pragma unroll
    for (int vt2 = 0; vt2 < 2; ++vt2) {
      int vl2 = 16 * vt2 + l15;
      f32x4 U = {};
#pragma unroll
      for (int ks = 0; ks < 2; ++ks)
        U = __builtin_amdgcn_mfma_f32_16x16x32_bf16(aU[ks], ldsv8(dBT, swzB(vl2, 16 * l4 + 64 * ks)), U, 0, 0, 0);
#pragma unroll
      for (int r = 0; r < 4; ++r) S[vt2][r] = wlv[r] * (S[vt2][r] + U[r]);
    }
    __syncthreads();
    // ---- Phase B2: S -> sBT, staging writes, snapshot ----
#pragma unroll
    for (int vt2 = 0; vt2 < 2; ++vt2) {
      int vl2 = 16 * vt2 + l15;
      uint2 pk;
      pk.x = (unsigned)f2bf(S[vt2][0]) | ((unsigned)f2bf(S[vt2][1]) << 16);
      pk.y = (unsigned)f2bf(S[vt2][2]) | ((unsigned)f2bf(S[vt2][3]) << 16);
      stsv8B(sBT, swzA(vl2, (16 * wave + 4 * l4) * 2), pk);
    }
    if (n < 63) { STAGE_WRITE(); rWlC = rWlN; }
    if ((n & 3) == 3) {
      int ns = n >> 2;
      size_t sb = (size_t)((ns * Bc + b) * Hc + h) * 16384;
#pragma unroll
      for (int vt2 = 0; vt2 < 2; ++vt2)
#pragma unroll
        for (int r = 0; r < 4; ++r) {
          int k = 16 * wave + 4 * l4 + r;
          snapb[sb + (size_t)k * 128 + v0 + 16 * vt2 + l15] = f2bf(S[vt2][r]);
        }
    }
    __syncthreads();
  }
#undef STAGE_LOAD
#undef STAGE_WRITE
}

// ---------------- snapshot helpers ----------------
__global__ void sdw_mul_bf16(const float* __restrict__ snap_down, const float* __restrict__ w,
                             unsigned short* __restrict__ sdwb) {
  int i = (blockIdx.x * 256 + threadIdx.x) * 4;
  float4 v = ld4(snap_down + i);
  int k = i & 16383;
  float4 ww = ld4(w + k);
  ushort4 o;
  o.x = f2bf(v.x * ww.x); o.y = f2bf(v.y * ww.y); o.z = f2bf(v.z * ww.z); o.w = f2bf(v.w * ww.w);
  *reinterpret_cast<ushort4*>(sdwb + i) = o;
}

__global__ __launch_bounds__(256) void snap_scale_kernel(const unsigned short* __restrict__ snapb,
                                                         float* __restrict__ scale) {
  int r = blockIdx.x;
  const unsigned short* row = snapb + (size_t)r * 16384;
  float s = 0.f;
  for (int ii = threadIdx.x * 4; ii < 16384; ii += 1024) {
    float4 x = ld4(row + ii);
    s += x.x * x.x + x.y * x.y + x.z * x.z + x.w * x.w;
  }
#pragma unroll
  for (int off = 32; off > 0; off >>= 1) s += __shfl_down(s, off, 64);
  __shared__ float red[4];
  if ((threadIdx.x & 63) == 0) red[threadIdx.x >> 6] = s;
  __syncthreads();
  if (threadIdx.x == 0) {
    float tot = red[0] + red[1] + red[2] + red[3];
    scale[r] = rsqrtf(tot * (1.f / 16384.f) + 1e-6f);
  }
}

__global__ void snap_reduce_scatter(const float* __restrict__ part,
                                    const float* __restrict__ scale,
                                    float* __restrict__ outp) {
  int idx = blockIdx.x * 256 + threadIdx.x;
  int l = idx & 127;
  int hh = (idx >> 7) & 15;
  int ns = (idx >> 11) & 15;
  int bb = idx >> 15;
  int r = (ns * Bc + bb) * Hc + hh;
  float s = 0.f;
#pragma unroll
  for (int z = 0; z < 16; ++z) s += part[(size_t)z * 65536 + r * 128 + l];
  outp[idx] = s * scale[r];
}

// ---------------- final rmsnorm * sigmoid(gate): wave-per-row ----------
__global__ __launch_bounds__(256) void out_norm_gate(unsigned short* __restrict__ attn_io,
                                                     const unsigned short* __restrict__ gate_raw,
                                                     const float* __restrict__ bgb,
                                                     const float* __restrict__ o_norm_w) {
  const int wave = threadIdx.x >> 6, lane = threadIdx.x & 63;
  const int blk = blockIdx.x * 4 + wave;  // (b*T + t)*H + h
  const int h = blk & 15;
  const size_t row = (size_t)(blk >> 4);
  const size_t base = (size_t)blk * Kc;
  ushort2 xv = *reinterpret_cast<const ushort2*>(attn_io + base + 2 * lane);
  float x0 = bf2f(xv.x), x1 = bf2f(xv.y);
  float ss = x0 * x0 + x1 * x1;
#pragma unroll
  for (int off = 32; off > 0; off >>= 1) ss += __shfl_xor(ss, off, 64);
  float inv = rsqrtf(ss * (1.f / 128.f) + 1e-6f);
  const int p0 = h * Kc + 2 * lane;
  ushort2 gv = *reinterpret_cast<const ushort2*>(gate_raw + row * Pc + p0);
  float g0 = bf2f(gv.x) + bgb[p0];
  float g1 = bf2f(gv.y) + bgb[p0 + 1];
  float o0 = x0 * inv * o_norm_w[2 * lane] * fsig(g0);
  float o1 = x1 * inv * o_norm_w[2 * lane + 1] * fsig(g1);
  ushort2 ov; ov.x = f2bf(o0); ov.y = f2bf(o1);
  *reinterpret_cast<ushort2*>(attn_io + base + 2 * lane) = ov;
}

// ---------------- launch ----------------
extern "C" void kernel_launch(void* const* d_in, const int* in_sizes, int n_in,
                              void* d_out, int out_size, void* d_ws, size_t ws_size,
                              hipStream_t stream) {
  (void)in_sizes; (void)n_in;
  const float* x        = (const float*)d_in[0];
  const float* Wq       = (const float*)d_in[1];
  const float* Wk       = (const float*)d_in[2];
  const float* Wv       = (const float*)d_in[3];
  const float* conv_q   = (const float*)d_in[4];
  const float* conv_k   = (const float*)d_in[5];
  const float* conv_v   = (const float*)d_in[6];
  const float* A_log    = (const float*)d_in[7];
  const float* dt_bias  = (const float*)d_in[8];
  const float* Wfa      = (const float*)d_in[9];
  const float* Wfb      = (const float*)d_in[10];
  const float* Wb       = (const float*)d_in[11];
  const float* Wga      = (const float*)d_in[12];
  const float* Wgb      = (const float*)d_in[13];
  const float* bgb      = (const float*)d_in[14];
  const float* o_norm_w = (const float*)d_in[15];
  const float* Wo       = (const float*)d_in[16];
  const float* snap_nw  = (const float*)d_in[17];
  const float* snap_down= (const float*)d_in[18];

  const size_t MP2 = (size_t)Mc * Pc * 2;
  const size_t NEED = 6 * MP2
                    + 2 * (size_t)Mc * Kc * 4
                    + (size_t)Mc * Hc * 4
                    + (size_t)Bc * Hc * NCc * Kc * 4;
  if (ws_size < NEED + 4096) {
    hipMemsetAsync(d_out, 0, (size_t)out_size * 4, stream);
    return;
  }
  char* w = (char*)d_ws;
  auto alloc = [&](size_t bytes) {
    char* r = w;
    w += (bytes + 255) & ~(size_t)255;
    return r;
  };
  unsigned short* q_lin = (unsigned short*)alloc(MP2);  // q,k,v contiguous (QKV-fused out)
  unsigned short* k_lin = (unsigned short*)alloc(MP2);
  unsigned short* v_lin = (unsigned short*)alloc(MP2);
  unsigned short* g_raw = (unsigned short*)alloc(MP2);
  unsigned short* evb   = (unsigned short*)alloc(MP2);
  unsigned short* ewb   = (unsigned short*)alloc(MP2);
  float* fa    = (float*)alloc((size_t)Mc * Kc * 4);    // fab + betabb (bf16)
  float* ga    = (float*)alloc((size_t)Mc * Kc * 4);
  float* betab = (float*)alloc((size_t)Mc * Hc * 4);    // unused (kept for NEED layout)
  float* wlast = (float*)alloc((size_t)Bc * Hc * NCc * Kc * 4);
  (void)betab;

  unsigned short* qt = (unsigned short*)d_out;
  unsigned short* u_ = (unsigned short*)((char*)d_out + MP2);

  unsigned short* xb    = evb;
  unsigned short* Wqb   = ewb;                 // [Wq;Wk;Wv] contiguous (6144 rows)
  unsigned short* Wkb   = ewb + 4194304;
  unsigned short* Wvb   = ewb + 8388608;
  unsigned short* Wfab  = ewb + 12582912;      // [Wfa;Wga;Wb_pad] contiguous (384 rows)
  unsigned short* Wgab  = ewb + 12845056;
  unsigned short* Wbp   = ewb + 13107200;      // padded Wb: 128x2048 bf16
  unsigned short* Wfbb  = ewb + 13369344;      // ends 13,631,488 < 16,777,216
  unsigned short* fab   = (unsigned short*)fa;              // 8192x128 bf16
  unsigned short* betabb= (unsigned short*)fa + 1048576;    // 8192x128 bf16 (exact fit)
  unsigned short* gab   = (unsigned short*)ga;

  unsigned short* intra = q_lin;
  unsigned short* Wob   = q_lin + 8388608;
  unsigned short* Wgbb  = q_lin + 12582912;
  unsigned short* attn  = k_lin;
  unsigned short* gate_raw = g_raw;
  unsigned short* snapb = v_lin;
  unsigned short* sdwb  = v_lin + (size_t)512 * 16384;
  float* partial   = (float*)ewb;
  float* snapscale = (float*)(ewb + 4400000);

  float* y = (float*)d_out;
  float* snaps_out = (float*)d_out + (size_t)Bc * Tc * Dc;

  // 0) casts (+ zero-padded Wb)
  cast_f32_bf16<<<16384, 256, 0, stream>>>(x, xb, Mc * Dc);
  cast_f32_bf16<<<4096, 256, 0, stream>>>(Wq, Wqb, Pc * Dc);
  cast_f32_bf16<<<4096, 256, 0, stream>>>(Wk, Wkb, Pc * Dc);
  cast_f32_bf16<<<4096, 256, 0, stream>>>(Wv, Wvb, Pc * Dc);
  cast_f32_bf16<<<256, 256, 0, stream>>>(Wfa, Wfab, Kc * Dc);
  cast_f32_bf16<<<256, 256, 0, stream>>>(Wga, Wgab, Kc * Dc);
  hipMemsetAsync(Wbp, 0, (size_t)128 * 2048 * 2, stream);
  cast_f32_bf16<<<32, 256, 0, stream>>>(Wb, Wbp, Hc * Dc);  // rows 0..15 valid
  cast_f32_bf16<<<256, 256, 0, stream>>>(Wfb, Wfbb, Pc * Kc);

  // 1) input GEMMs (bf16 MFMA): fused QKV + fused fa/ga/beta + g_raw
  gemm_nt_mfma_qkv<<<dim3(64, 48), 256, 0, stream>>>(xb, Wqb, q_lin, Dc);
  gemm_nt_mfma_fgb<<<dim3(64, 3), 256, 0, stream>>>(xb, Wfab, fab, gab, betabb, Dc);
  gemm_nt_mfma<unsigned short><<<dim3(64, 16), 256, 0, stream>>>(fab, Wfbb, g_raw, Pc, Kc);

  // 2) chunk prep (wave-per-chunk; beta bf16 stride 128)
  chunk_prep<<<Bc * Hc * NCc / 4, 256, 0, stream>>>(q_lin, k_lin, v_lin, g_raw, betabb, conv_q,
                                                    conv_k, conv_v, A_log, dt_bias, qt, u_, evb,
                                                    ewb, wlast);

  // 3) late casts into q_lin's dead tail
  cast_f32_bf16<<<4096, 256, 0, stream>>>(Wo, Wob, Dc * Pc);
  cast_f32_bf16<<<256, 256, 0, stream>>>(Wgb, Wgbb, Pc * Kc);

  // chunk solve (also transposes u -> uT in place)
  chunk_solve_mfma<<<Bc * Hc * NCc, 256, 0, stream>>>(qt, u_, evb, ewb, intra);

  // 4) gate projection
  gemm_nt_mfma<unsigned short><<<dim3(64, 16), 256, 0, stream>>>(gab, Wgbb, gate_raw, Pc, Kc);

  // 5) MFMA scan, v-split x4 (u_ holds uT)
  scan_mfma<<<Bc * Hc * 4, 512, 0, stream>>>(qt, u_, evb, ewb, intra, wlast, attn, snapb);

  // 6) snapshots
  sdw_mul_bf16<<<2048, 256, 0, stream>>>(snap_down, snap_nw, sdwb);
  snap_scale_kernel<<<512, 256, 0, stream>>>(snapb, snapscale);
  gemm_nt_mfma_sk<<<dim3(4, 1, 16), 256, 0, stream>>>(snapb, sdwb, partial, 128, 16384, 1024, 512);
  snap_reduce_scatter<<<256, 256, 0, stream>>>(partial, snapscale, snaps_out);

  // 7) output norm*gate + final projection
  out_norm_gate<<<Mc * Hc / 4, 256, 0, stream>>>(attn, gate_raw, bgb, o_norm_w);
  gemm_nt_mfma<float><<<dim3(64, 16), 256, 0, stream>>>(attn, Wob, y, Dc, Pc);
}